// Round 1
// baseline (1019.225 us; speedup 1.0000x reference)
//
#include <hip/hip_runtime.h>
#include <hip/hip_bf16.h>

#define NN 1024
#define HID 128
#define NHEADS 4
#define HDD 32
#define NL 3

// ---- ws layout (float-word units) ----
constexpr int OFF_CONV = 16;
constexpr int OFF_NF   = OFF_CONV;            // 3072
constexpr int OFF_WP   = OFF_NF  + 3072;      // 384
constexpr int OFF_BP   = OFF_WP  + 384;       // 128
constexpr int OFF_WL   = OFF_BP  + 128;       // 49152
constexpr int OFF_WR   = OFF_WL  + 49152;     // 49152
constexpr int OFF_WVW  = OFF_WR  + 49152;     // 49152
constexpr int OFF_ATT  = OFF_WVW + 49152;     // 96
constexpr int OFF_GAM  = OFF_ATT + 96;        // 384
constexpr int OFF_BET  = OFF_GAM + 384;       // 384
constexpr int OFF_WN1  = OFF_BET + 384;       // 8192
constexpr int OFF_BN1  = OFF_WN1 + 8192;      // 64
constexpr int OFF_WN2  = OFF_BN1 + 64;        // 64
constexpr int OFF_BN2  = OFF_WN2 + 64;        // 1
constexpr int OFF_WD1  = OFF_BN2 + 1;         // 8192
constexpr int OFF_BD1  = OFF_WD1 + 8192;      // 64
constexpr int OFF_WD2  = OFF_BD1 + 64;        // 128
constexpr int OFF_BD2  = OFF_WD2 + 128;       // 2
constexpr int OFF_WV1  = OFF_BD2 + 2;         // 8192
constexpr int OFF_BV1  = OFF_WV1 + 8192;      // 64
constexpr int OFF_WV2  = OFF_BV1 + 64;        // 64
constexpr int OFF_BV2  = OFF_WV2 + 64;        // 1
constexpr int OFF_CONV_END = OFF_BV2 + 1;
constexpr int CONV_TOTAL = OFF_CONV_END - OFF_CONV;
constexpr int OFF_MASK = 176960;              // 1024*32 uint32 words
constexpr int OFF_H    = OFF_MASK + NN*32;
constexpr int OFF_WLH  = OFF_H   + NN*HID;    // normal [i][128]
constexpr int OFF_WRH  = OFF_WLH + NN*HID;    // TRANSPOSED [dq=32][j=1024][4]
constexpr int OFF_WVH  = OFF_WRH + NN*HID;    // TRANSPOSED [dq=32][j=1024][4]
constexpr int OFF_CL   = OFF_WVH + NN*HID;    // [h][i]  0.6*att.wl
constexpr int OFF_CR   = OFF_CL  + NHEADS*NN; // [h][j]  0.6*att.wr

__device__ __forceinline__ float bf2f(unsigned short u) {
    return __uint_as_float(((unsigned)u) << 16);
}
__device__ __forceinline__ void store_out(void* out, int idx, float v, bool bf) {
    if (bf) {
        unsigned u = __float_as_uint(v);
        unsigned r = (u + 0x7FFFu + ((u >> 16) & 1u)) >> 16;
        ((unsigned short*)out)[idx] = (unsigned short)r;
    } else {
        ((float*)out)[idx] = v;
    }
}
// per-wave dtype sniff: fp32 normals have exponent field in [110,140];
// packed bf16 pairs viewed as fp32 essentially never do. Call from ALL lanes.
__device__ __forceinline__ bool detect_bf(const unsigned* nf) {
    unsigned w = nf[threadIdx.x & 63];
    int e = (int)((w >> 23) & 0xFFu);
    unsigned long long b = __ballot(e >= 110 && e <= 140);
    return __popcll(b) < 32;
}

// ---- convert all non-adj params to fp32 in ws ----
struct P21 { const void* p[21]; };
__device__ const int g_sizes[21] = {3072,384,128,49152,49152,49152,96,384,384,
                                    8192,64,64,1,8192,64,128,2,8192,64,64,1};
__device__ const int g_dsts[21] = {OFF_NF,OFF_WP,OFF_BP,OFF_WL,OFF_WR,OFF_WVW,OFF_ATT,
                                   OFF_GAM,OFF_BET,OFF_WN1,OFF_BN1,OFF_WN2,OFF_BN2,
                                   OFF_WD1,OFF_BD1,OFF_WD2,OFF_BD2,OFF_WV1,OFF_BV1,
                                   OFF_WV2,OFF_BV2};
__global__ __launch_bounds__(256) void k_convert(P21 in, const unsigned* nf, float* ws) {
    bool bf = detect_bf(nf);
    int g = blockIdx.x * blockDim.x + threadIdx.x;
    if (g >= CONV_TOTAL) return;
    int rem = g, s = 0;
    while (s < 21 && rem >= g_sizes[s]) { rem -= g_sizes[s]; s++; }
    if (s >= 21) return;
    float v;
    if (bf) v = bf2f(((const unsigned short*)in.p[s])[rem]);
    else    v = ((const float*)in.p[s])[rem];
    ws[g_dsts[s] + rem] = v;
}

// ---- adj -> packed bitmask ----
__global__ __launch_bounds__(1024) void k_mask(const void* adj, const unsigned* nf, float* ws) {
    bool bf = detect_bf(nf);
    unsigned* mask = (unsigned*)(ws + OFF_MASK);
    int i = blockIdx.x, t = threadIdx.x;
    float v = bf ? bf2f(((const unsigned short*)adj)[i * NN + t])
                 : ((const float*)adj)[i * NN + t];
    unsigned long long b = __ballot(v > 0.5f);
    int lane = t & 63, wv = t >> 6;
    if (lane == 0) {
        mask[i * 32 + wv * 2]     = (unsigned)b;
        mask[i * 32 + wv * 2 + 1] = (unsigned)(b >> 32);
    }
}

// ---- h0 = relu(nf @ Wp + bp) ----
__global__ __launch_bounds__(128) void k_h0(float* ws) {
    int i = blockIdx.x, c = threadIdx.x;
    const float* nf = ws + OFF_NF;
    const float* Wp = ws + OFF_WP;
    float a = ws[OFF_BP + c];
    #pragma unroll
    for (int k = 0; k < 3; k++) a += nf[i * 3 + k] * Wp[k * HID + c];
    ws[OFF_H + i * HID + c] = fmaxf(a, 0.0f);
}

// ---- per layer: wlh = h@Wl (normal + cl), wrh/wvh = h@{Wr,Wv} (transposed + cr) ----
__global__ __launch_bounds__(128) void k_mm3(float* ws, int l) {
    __shared__ float hs[4][HID];
    int c = threadIdx.x, i0 = blockIdx.x * 4, which = blockIdx.y;
    const float* h = ws + OFF_H;
    #pragma unroll
    for (int r = 0; r < 4; r++) hs[r][c] = h[(i0 + r) * HID + c];
    __syncthreads();
    int woff = (which == 0) ? OFF_WL : (which == 1) ? OFF_WR : OFF_WVW;
    const float* W = ws + woff + l * HID * HID;
    float a[4] = {0,0,0,0};
    #pragma unroll 4
    for (int k = 0; k < HID; k++) {
        float w = W[k * HID + c];
        #pragma unroll
        for (int r = 0; r < 4; r++) a[r] += hs[r][k] * w;
    }
    if (which == 0) {
        #pragma unroll
        for (int r = 0; r < 4; r++) ws[OFF_WLH + (i0 + r) * HID + c] = a[r];
        float att = ws[OFF_ATT + l * HDD + (c & 31)];
        #pragma unroll
        for (int r = 0; r < 4; r++) {
            float t = att * a[r];
            #pragma unroll
            for (int off = 1; off < 32; off <<= 1) t += __shfl_xor(t, off, 64);
            if ((c & 31) == 0) ws[OFF_CL + (c >> 5) * NN + (i0 + r)] = 0.6f * t;
        }
    } else {
        int doff = (which == 1) ? OFF_WRH : OFF_WVH;
        // transposed-tiled: element (j, c) -> [c>>2][j][c&3]
        #pragma unroll
        for (int r = 0; r < 4; r++)
            ws[doff + (c >> 2) * (NN * 4) + (i0 + r) * 4 + (c & 3)] = a[r];
        if (which == 1) {
            float att = ws[OFF_ATT + l * HDD + (c & 31)];
            #pragma unroll
            for (int r = 0; r < 4; r++) {
                float t = att * a[r];
                #pragma unroll
                for (int off = 1; off < 32; off <<= 1) t += __shfl_xor(t, off, 64);
                if ((c & 31) == 0) ws[OFF_CR + (c >> 5) * NN + (i0 + r)] = 0.6f * t;
            }
        }
    }
}

// ---- per layer: fused attention, lane-per-j, coalesced transposed operands ----
// block = 256 threads = 4 waves; wave w = head w; one block per node i.
// e_ij = 0.6*att.(wl_i+wr_j) + sum_d 0.4*att_d*|wl_id + wr_jd|   (exact leaky split)
__global__ __launch_bounds__(256, 4) void k_attn(float* ws, int l) {
    int i = blockIdx.x, t = threadIdx.x;
    int lane = t & 63;
    int h = __builtin_amdgcn_readfirstlane(t >> 6);
    __shared__ unsigned mrow[32];
    __shared__ float part[4][64][33];   // [head][lane][d] partial aggs, pad 33
    __shared__ float invs[4];
    __shared__ float agg_s[HID];
    __shared__ float red[4];
    const unsigned* mask = (const unsigned*)(ws + OFF_MASK);
    if (t < 32) mrow[t] = mask[i * 32 + t];
    __syncthreads();

    // per-lane 16-bit mask: bit jc = adjacency of j = jc*64+lane
    unsigned mbits = 0;
    #pragma unroll
    for (int jc = 0; jc < 16; jc++)
        mbits |= ((mrow[jc * 2 + (lane >> 5)] >> (lane & 31)) & 1u) << jc;

    // wave-uniform vectors -> registers (0.4 folded into att)
    float att_r[32], wl_r[32];
    const float* attp = ws + OFF_ATT + l * HDD;
    const float* wlp  = ws + OFF_WLH + i * HID + h * HDD;
    #pragma unroll
    for (int d = 0; d < 32; d++) { att_r[d] = 0.4f * attp[d]; wl_r[d] = wlp[d]; }
    float cl6 = ws[OFF_CL + h * NN + i];

    const float* wrT = ws + OFF_WRH + h * 8 * (NN * 4) + lane * 4;
    const float* wvT = ws + OFF_WVH + h * 8 * (NN * 4) + lane * 4;
    const float* crp = ws + OFF_CR + h * NN;

    // phase 1: e_j per lane (dense, branch-free), track lane max
    float e[16];
    float m = -1e30f;
    #pragma unroll
    for (int jc = 0; jc < 16; jc++) {
        float cr6 = crp[jc * 64 + lane];
        float acc = 0.0f;
        #pragma unroll
        for (int dq = 0; dq < 8; dq++) {
            float4 w = *(const float4*)(wrT + dq * (NN * 4) + jc * 256);
            acc = fmaf(att_r[dq*4+0], fabsf(wl_r[dq*4+0] + w.x), acc);
            acc = fmaf(att_r[dq*4+1], fabsf(wl_r[dq*4+1] + w.y), acc);
            acc = fmaf(att_r[dq*4+2], fabsf(wl_r[dq*4+2] + w.z), acc);
            acc = fmaf(att_r[dq*4+3], fabsf(wl_r[dq*4+3] + w.w), acc);
        }
        float ej = (cl6 + cr6) + acc;
        ej = ((mbits >> jc) & 1u) ? ej : -1e9f;
        e[jc] = ej;
        m = fmaxf(m, ej);
    }
    #pragma unroll
    for (int off = 32; off > 0; off >>= 1) m = fmaxf(m, __shfl_xor(m, off, 64));

    // phase 2: pe = exp(e - m) (masked -> exact 0), accumulate pe * v
    float acc[32];
    #pragma unroll
    for (int d = 0; d < 32; d++) acc[d] = 0.0f;
    float lsum = 0.0f;
    #pragma unroll
    for (int jc = 0; jc < 16; jc++) {
        float pe = __expf(e[jc] - m);
        lsum += pe;
        #pragma unroll
        for (int dq = 0; dq < 8; dq++) {
            float4 v = *(const float4*)(wvT + dq * (NN * 4) + jc * 256);
            acc[dq*4+0] = fmaf(pe, v.x, acc[dq*4+0]);
            acc[dq*4+1] = fmaf(pe, v.y, acc[dq*4+1]);
            acc[dq*4+2] = fmaf(pe, v.z, acc[dq*4+2]);
            acc[dq*4+3] = fmaf(pe, v.w, acc[dq*4+3]);
        }
    }
    #pragma unroll
    for (int off = 32; off > 0; off >>= 1) lsum += __shfl_xor(lsum, off, 64);
    if (lane == 0) invs[h] = 1.0f / lsum;
    #pragma unroll
    for (int d = 0; d < 32; d++) part[h][lane][d] = acc[d];
    __syncthreads();

    // cross-lane reduce via LDS: thread t -> (head, d, lane-half)
    {
        int h2 = t >> 6, idx = t & 63, d = idx & 31, half = idx >> 5;
        float s = 0.0f;
        #pragma unroll
        for (int lq = 0; lq < 32; lq++) s += part[h2][half * 32 + lq][d];
        s += __shfl_xor(s, 32, 64);
        if (half == 0) agg_s[h2 * 32 + d] = s * invs[h2];
    }
    __syncthreads();

    // layernorm over 128 features + residual, threads 0..127
    float s = 0.f, s2 = 0.f, agg = 0.f;
    if (t < HID) {
        agg = agg_s[t];
        s = agg; s2 = agg * agg;
        #pragma unroll
        for (int off = 32; off > 0; off >>= 1) {
            s  += __shfl_xor(s,  off, 64);
            s2 += __shfl_xor(s2, off, 64);
        }
        if ((t & 63) == 0) { red[(t >> 6) * 2] = s; red[(t >> 6) * 2 + 1] = s2; }
    }
    __syncthreads();
    if (t < HID) {
        float ts = red[0] + red[2], ts2 = red[1] + red[3];
        float mu  = ts  * (1.0f / HID);
        float var = ts2 * (1.0f / HID) - mu * mu;
        float g  = ws[OFF_GAM + l * HID + t];
        float be = ws[OFF_BET + l * HID + t];
        float o = (agg - mu) * rsqrtf(var + 1e-5f) * g + be;
        ws[OFF_H + i * HID + t] += fmaxf(o, 0.0f);
    }
}

// ---- node_logits + delta_mu heads ----
__global__ __launch_bounds__(64) void k_heads(float* ws, const unsigned* nf, void* out) {
    bool bf = detect_bf(nf);
    int i = blockIdx.x, t = threadIdx.x;
    __shared__ float hrow[HID];
    hrow[t]      = ws[OFF_H + i * HID + t];
    hrow[t + 64] = ws[OFF_H + i * HID + t + 64];
    __syncthreads();
    const float* Wn1 = ws + OFF_WN1;
    const float* Wd1 = ws + OFF_WD1;
    float z1 = ws[OFF_BN1 + t], zd = ws[OFF_BD1 + t];
    #pragma unroll 4
    for (int k = 0; k < HID; k++) {
        float hk = hrow[k];
        z1 += hk * Wn1[k * 64 + t];
        zd += hk * Wd1[k * 64 + t];
    }
    z1 = fmaxf(z1, 0.0f); zd = fmaxf(zd, 0.0f);
    float lg = z1 * ws[OFF_WN2 + t];
    float d0 = zd * ws[OFF_WD2 + t * 2 + 0];
    float d1 = zd * ws[OFF_WD2 + t * 2 + 1];
    #pragma unroll
    for (int off = 32; off > 0; off >>= 1) {
        lg += __shfl_xor(lg, off, 64);
        d0 += __shfl_xor(d0, off, 64);
        d1 += __shfl_xor(d1, off, 64);
    }
    if (t == 0) {
        store_out(out, i,              lg + ws[OFF_BN2],     bf);
        store_out(out, NN + i * 2 + 0, d0 + ws[OFF_BD2 + 0], bf);
        store_out(out, NN + i * 2 + 1, d1 + ws[OFF_BD2 + 1], bf);
    }
}

// ---- pooled mean + value head ----
__global__ __launch_bounds__(1024) void k_value(float* ws, const unsigned* nf, void* out) {
    bool bf = detect_bf(nf);
    __shared__ float part[8 * HID];
    __shared__ float pooled[HID];
    int t = threadIdx.x;
    int g = t >> 7, c = t & 127;
    float s = 0.0f;
    for (int r = 0; r < 128; r++) s += ws[OFF_H + (g * 128 + r) * HID + c];
    part[g * HID + c] = s;
    __syncthreads();
    if (t < HID) {
        float p = 0.0f;
        #pragma unroll
        for (int gg = 0; gg < 8; gg++) p += part[gg * HID + t];
        pooled[t] = p * (1.0f / NN);
    }
    __syncthreads();
    if (t < 64) {
        float z = ws[OFF_BV1 + t];
        for (int k = 0; k < HID; k++) z += pooled[k] * ws[OFF_WV1 + k * 64 + t];
        z = fmaxf(z, 0.0f);
        float pv = z * ws[OFF_WV2 + t];
        #pragma unroll
        for (int off = 32; off > 0; off >>= 1) pv += __shfl_xor(pv, off, 64);
        if (t == 0) store_out(out, 3072, pv + ws[OFF_BV2], bf);
    }
}

extern "C" void kernel_launch(void* const* d_in, const int* in_sizes, int n_in,
                              void* d_out, int out_size, void* d_ws, size_t ws_size,
                              hipStream_t stream) {
    float* ws = (float*)d_ws;
    const unsigned* nf = (const unsigned*)d_in[0];

    P21 ptrs;
    const int map[21] = {0,2,3,4,5,6,7,8,9,10,11,12,13,14,15,16,17,18,19,20,21};
    for (int s = 0; s < 21; s++) ptrs.p[s] = d_in[map[s]];
    k_convert<<<(CONV_TOTAL + 255) / 256, 256, 0, stream>>>(ptrs, nf, ws);

    k_mask<<<NN, 1024, 0, stream>>>(d_in[1], nf, ws);
    k_h0<<<NN, 128, 0, stream>>>(ws);

    for (int l = 0; l < NL; l++) {
        k_mm3<<<dim3(NN / 4, 3), 128, 0, stream>>>(ws, l);
        k_attn<<<NN, 256, 0, stream>>>(ws, l);
    }

    k_heads<<<NN, 64, 0, stream>>>(ws, nf, d_out);
    k_value<<<1, 1024, 0, stream>>>(ws, nf, d_out);
}

// Round 2
// 538.685 us; speedup vs baseline: 1.8921x; 1.8921x over previous
//
#include <hip/hip_runtime.h>
#include <hip/hip_bf16.h>

#define NN 1024
#define HID 128
#define NHEADS 4
#define HDD 32
#define NL 3

// ---- ws layout (float-word units) ----
constexpr int OFF_CONV = 16;
constexpr int OFF_NF   = OFF_CONV;            // 3072
constexpr int OFF_WP   = OFF_NF  + 3072;      // 384
constexpr int OFF_BP   = OFF_WP  + 384;       // 128
constexpr int OFF_WL   = OFF_BP  + 128;       // 49152
constexpr int OFF_WR   = OFF_WL  + 49152;     // 49152
constexpr int OFF_WVW  = OFF_WR  + 49152;     // 49152
constexpr int OFF_ATT  = OFF_WVW + 49152;     // 96
constexpr int OFF_GAM  = OFF_ATT + 96;        // 384
constexpr int OFF_BET  = OFF_GAM + 384;       // 384
constexpr int OFF_WN1  = OFF_BET + 384;       // 8192
constexpr int OFF_BN1  = OFF_WN1 + 8192;      // 64
constexpr int OFF_WN2  = OFF_BN1 + 64;        // 64
constexpr int OFF_BN2  = OFF_WN2 + 64;        // 1
constexpr int OFF_WD1  = OFF_BN2 + 1;         // 8192
constexpr int OFF_BD1  = OFF_WD1 + 8192;      // 64
constexpr int OFF_WD2  = OFF_BD1 + 64;        // 128
constexpr int OFF_BD2  = OFF_WD2 + 128;       // 2
constexpr int OFF_WV1  = OFF_BD2 + 2;         // 8192
constexpr int OFF_BV1  = OFF_WV1 + 8192;      // 64
constexpr int OFF_WV2  = OFF_BV1 + 64;        // 64
constexpr int OFF_BV2  = OFF_WV2 + 64;        // 1
constexpr int OFF_CONV_END = OFF_BV2 + 1;
constexpr int CONV_TOTAL = OFF_CONV_END - OFF_CONV;
constexpr int OFF_MASK = 176960;              // 1024*32 uint32 words
constexpr int OFF_H    = OFF_MASK + NN*32;
constexpr int OFF_WLH  = OFF_H   + NN*HID;    // normal [i][128]
constexpr int OFF_WRH  = OFF_WLH + NN*HID;    // TRANSPOSED [dq=32][j=1024][4]
constexpr int OFF_WVH  = OFF_WRH + NN*HID;    // TRANSPOSED [dq=32][j=1024][4]
constexpr int OFF_CL   = OFF_WVH + NN*HID;    // [h][i]  0.6*att.wl
constexpr int OFF_CR   = OFF_CL  + NHEADS*NN; // [h][j]  0.6*att.wr

__device__ __forceinline__ float bf2f(unsigned short u) {
    return __uint_as_float(((unsigned)u) << 16);
}
__device__ __forceinline__ void store_out(void* out, int idx, float v, bool bf) {
    if (bf) {
        unsigned u = __float_as_uint(v);
        unsigned r = (u + 0x7FFFu + ((u >> 16) & 1u)) >> 16;
        ((unsigned short*)out)[idx] = (unsigned short)r;
    } else {
        ((float*)out)[idx] = v;
    }
}
// per-wave dtype sniff: fp32 normals have exponent field in [110,140];
// packed bf16 pairs viewed as fp32 essentially never do. Call from ALL lanes.
__device__ __forceinline__ bool detect_bf(const unsigned* nf) {
    unsigned w = nf[threadIdx.x & 63];
    int e = (int)((w >> 23) & 0xFFu);
    unsigned long long b = __ballot(e >= 110 && e <= 140);
    return __popcll(b) < 32;
}

// ---- convert all non-adj params to fp32 in ws ----
struct P21 { const void* p[21]; };
__device__ const int g_sizes[21] = {3072,384,128,49152,49152,49152,96,384,384,
                                    8192,64,64,1,8192,64,128,2,8192,64,64,1};
__device__ const int g_dsts[21] = {OFF_NF,OFF_WP,OFF_BP,OFF_WL,OFF_WR,OFF_WVW,OFF_ATT,
                                   OFF_GAM,OFF_BET,OFF_WN1,OFF_BN1,OFF_WN2,OFF_BN2,
                                   OFF_WD1,OFF_BD1,OFF_WD2,OFF_BD2,OFF_WV1,OFF_BV1,
                                   OFF_WV2,OFF_BV2};
__global__ __launch_bounds__(256) void k_convert(P21 in, const unsigned* nf, float* ws) {
    bool bf = detect_bf(nf);
    int g = blockIdx.x * blockDim.x + threadIdx.x;
    if (g >= CONV_TOTAL) return;
    int rem = g, s = 0;
    while (s < 21 && rem >= g_sizes[s]) { rem -= g_sizes[s]; s++; }
    if (s >= 21) return;
    float v;
    if (bf) v = bf2f(((const unsigned short*)in.p[s])[rem]);
    else    v = ((const float*)in.p[s])[rem];
    ws[g_dsts[s] + rem] = v;
}

// ---- adj -> packed bitmask ----
__global__ __launch_bounds__(1024) void k_mask(const void* adj, const unsigned* nf, float* ws) {
    bool bf = detect_bf(nf);
    unsigned* mask = (unsigned*)(ws + OFF_MASK);
    int i = blockIdx.x, t = threadIdx.x;
    float v = bf ? bf2f(((const unsigned short*)adj)[i * NN + t])
                 : ((const float*)adj)[i * NN + t];
    unsigned long long b = __ballot(v > 0.5f);
    int lane = t & 63, wv = t >> 6;
    if (lane == 0) {
        mask[i * 32 + wv * 2]     = (unsigned)b;
        mask[i * 32 + wv * 2 + 1] = (unsigned)(b >> 32);
    }
}

// ---- h0 = relu(nf @ Wp + bp) ----
__global__ __launch_bounds__(128) void k_h0(float* ws) {
    int i = blockIdx.x, c = threadIdx.x;
    const float* nf = ws + OFF_NF;
    const float* Wp = ws + OFF_WP;
    float a = ws[OFF_BP + c];
    #pragma unroll
    for (int k = 0; k < 3; k++) a += nf[i * 3 + k] * Wp[k * HID + c];
    ws[OFF_H + i * HID + c] = fmaxf(a, 0.0f);
}

// ---- per layer: wlh = h@Wl (normal + cl), wrh/wvh = h@{Wr,Wv} (transposed + cr) ----
__global__ __launch_bounds__(128) void k_mm3(float* ws, int l) {
    __shared__ float hs[4][HID];
    int c = threadIdx.x, i0 = blockIdx.x * 4, which = blockIdx.y;
    const float* h = ws + OFF_H;
    #pragma unroll
    for (int r = 0; r < 4; r++) hs[r][c] = h[(i0 + r) * HID + c];
    __syncthreads();
    int woff = (which == 0) ? OFF_WL : (which == 1) ? OFF_WR : OFF_WVW;
    const float* W = ws + woff + l * HID * HID;
    float a[4] = {0,0,0,0};
    #pragma unroll 4
    for (int k = 0; k < HID; k++) {
        float w = W[k * HID + c];
        #pragma unroll
        for (int r = 0; r < 4; r++) a[r] += hs[r][k] * w;
    }
    if (which == 0) {
        #pragma unroll
        for (int r = 0; r < 4; r++) ws[OFF_WLH + (i0 + r) * HID + c] = a[r];
        float att = ws[OFF_ATT + l * HDD + (c & 31)];
        #pragma unroll
        for (int r = 0; r < 4; r++) {
            float t = att * a[r];
            #pragma unroll
            for (int off = 1; off < 32; off <<= 1) t += __shfl_xor(t, off, 64);
            if ((c & 31) == 0) ws[OFF_CL + (c >> 5) * NN + (i0 + r)] = 0.6f * t;
        }
    } else {
        int doff = (which == 1) ? OFF_WRH : OFF_WVH;
        // transposed-tiled: element (j, c) -> [c>>2][j][c&3]
        #pragma unroll
        for (int r = 0; r < 4; r++)
            ws[doff + (c >> 2) * (NN * 4) + (i0 + r) * 4 + (c & 3)] = a[r];
        if (which == 1) {
            float att = ws[OFF_ATT + l * HDD + (c & 31)];
            #pragma unroll
            for (int r = 0; r < 4; r++) {
                float t = att * a[r];
                #pragma unroll
                for (int off = 1; off < 32; off <<= 1) t += __shfl_xor(t, off, 64);
                if ((c & 31) == 0) ws[OFF_CR + (c >> 5) * NN + (i0 + r)] = 0.6f * t;
            }
        }
    }
}

// ---- per layer: fused attention, lane-per-j, coalesced transposed operands ----
// block = 256 threads = 4 waves; wave w = head w; one block per node i.
// e_ij = 0.6*att.(wl_i+wr_j) + sum_d 0.4*att_d*|wl_id + wr_jd|   (exact leaky split)
// NOTE: no min-waves launch bound — the (256,4) variant capped the unified
// VGPR/AGPR budget at 128/wave and spilled the ~112-float register state to
// scratch (451 MB WRITE_SIZE/dispatch, 4% VALUBusy). Unbounded, the compiler
// parks the arrays in AGPRs (round-0 evidence: VGPR=52, zero scratch traffic).
__global__ __launch_bounds__(256) void k_attn(float* ws, int l) {
    int i = blockIdx.x, t = threadIdx.x;
    int lane = t & 63;
    int h = __builtin_amdgcn_readfirstlane(t >> 6);
    __shared__ unsigned mrow[32];
    __shared__ float part[4][64][33];   // [head][lane][d] partial aggs, pad 33
    __shared__ float invs[4];
    __shared__ float agg_s[HID];
    __shared__ float red[4];
    const unsigned* mask = (const unsigned*)(ws + OFF_MASK);
    if (t < 32) mrow[t] = mask[i * 32 + t];
    __syncthreads();

    // per-lane 16-bit mask: bit jc = adjacency of j = jc*64+lane
    unsigned mbits = 0;
    #pragma unroll
    for (int jc = 0; jc < 16; jc++)
        mbits |= ((mrow[jc * 2 + (lane >> 5)] >> (lane & 31)) & 1u) << jc;

    // wave-uniform vectors -> registers (0.4 folded into att)
    float att_r[32], wl_r[32];
    const float* attp = ws + OFF_ATT + l * HDD;
    const float* wlp  = ws + OFF_WLH + i * HID + h * HDD;
    #pragma unroll
    for (int d = 0; d < 32; d++) { att_r[d] = 0.4f * attp[d]; wl_r[d] = wlp[d]; }
    float cl6 = ws[OFF_CL + h * NN + i];

    const float* wrT = ws + OFF_WRH + h * 8 * (NN * 4) + lane * 4;
    const float* wvT = ws + OFF_WVH + h * 8 * (NN * 4) + lane * 4;
    const float* crp = ws + OFF_CR + h * NN;

    // phase 1: e_j per lane (dense, branch-free), track lane max
    float e[16];
    float m = -1e30f;
    #pragma unroll
    for (int jc = 0; jc < 16; jc++) {
        float cr6 = crp[jc * 64 + lane];
        float acc = 0.0f;
        #pragma unroll
        for (int dq = 0; dq < 8; dq++) {
            float4 w = *(const float4*)(wrT + dq * (NN * 4) + jc * 256);
            acc = fmaf(att_r[dq*4+0], fabsf(wl_r[dq*4+0] + w.x), acc);
            acc = fmaf(att_r[dq*4+1], fabsf(wl_r[dq*4+1] + w.y), acc);
            acc = fmaf(att_r[dq*4+2], fabsf(wl_r[dq*4+2] + w.z), acc);
            acc = fmaf(att_r[dq*4+3], fabsf(wl_r[dq*4+3] + w.w), acc);
        }
        float ej = (cl6 + cr6) + acc;
        ej = ((mbits >> jc) & 1u) ? ej : -1e9f;
        e[jc] = ej;
        m = fmaxf(m, ej);
    }
    #pragma unroll
    for (int off = 32; off > 0; off >>= 1) m = fmaxf(m, __shfl_xor(m, off, 64));

    // phase 2: pe = exp(e - m) (masked -> exact 0), accumulate pe * v
    float acc[32];
    #pragma unroll
    for (int d = 0; d < 32; d++) acc[d] = 0.0f;
    float lsum = 0.0f;
    #pragma unroll
    for (int jc = 0; jc < 16; jc++) {
        float pe = __expf(e[jc] - m);
        lsum += pe;
        #pragma unroll
        for (int dq = 0; dq < 8; dq++) {
            float4 v = *(const float4*)(wvT + dq * (NN * 4) + jc * 256);
            acc[dq*4+0] = fmaf(pe, v.x, acc[dq*4+0]);
            acc[dq*4+1] = fmaf(pe, v.y, acc[dq*4+1]);
            acc[dq*4+2] = fmaf(pe, v.z, acc[dq*4+2]);
            acc[dq*4+3] = fmaf(pe, v.w, acc[dq*4+3]);
        }
    }
    #pragma unroll
    for (int off = 32; off > 0; off >>= 1) lsum += __shfl_xor(lsum, off, 64);
    if (lane == 0) invs[h] = 1.0f / lsum;
    #pragma unroll
    for (int d = 0; d < 32; d++) part[h][lane][d] = acc[d];
    __syncthreads();

    // cross-lane reduce via LDS: thread t -> (head, d, lane-half)
    {
        int h2 = t >> 6, idx = t & 63, d = idx & 31, half = idx >> 5;
        float s = 0.0f;
        #pragma unroll
        for (int lq = 0; lq < 32; lq++) s += part[h2][half * 32 + lq][d];
        s += __shfl_xor(s, 32, 64);
        if (half == 0) agg_s[h2 * 32 + d] = s * invs[h2];
    }
    __syncthreads();

    // layernorm over 128 features + residual, threads 0..127
    float s = 0.f, s2 = 0.f, agg = 0.f;
    if (t < HID) {
        agg = agg_s[t];
        s = agg; s2 = agg * agg;
        #pragma unroll
        for (int off = 32; off > 0; off >>= 1) {
            s  += __shfl_xor(s,  off, 64);
            s2 += __shfl_xor(s2, off, 64);
        }
        if ((t & 63) == 0) { red[(t >> 6) * 2] = s; red[(t >> 6) * 2 + 1] = s2; }
    }
    __syncthreads();
    if (t < HID) {
        float ts = red[0] + red[2], ts2 = red[1] + red[3];
        float mu  = ts  * (1.0f / HID);
        float var = ts2 * (1.0f / HID) - mu * mu;
        float g  = ws[OFF_GAM + l * HID + t];
        float be = ws[OFF_BET + l * HID + t];
        float o = (agg - mu) * rsqrtf(var + 1e-5f) * g + be;
        ws[OFF_H + i * HID + t] += fmaxf(o, 0.0f);
    }
}

// ---- node_logits + delta_mu heads ----
__global__ __launch_bounds__(64) void k_heads(float* ws, const unsigned* nf, void* out) {
    bool bf = detect_bf(nf);
    int i = blockIdx.x, t = threadIdx.x;
    __shared__ float hrow[HID];
    hrow[t]      = ws[OFF_H + i * HID + t];
    hrow[t + 64] = ws[OFF_H + i * HID + t + 64];
    __syncthreads();
    const float* Wn1 = ws + OFF_WN1;
    const float* Wd1 = ws + OFF_WD1;
    float z1 = ws[OFF_BN1 + t], zd = ws[OFF_BD1 + t];
    #pragma unroll 4
    for (int k = 0; k < HID; k++) {
        float hk = hrow[k];
        z1 += hk * Wn1[k * 64 + t];
        zd += hk * Wd1[k * 64 + t];
    }
    z1 = fmaxf(z1, 0.0f); zd = fmaxf(zd, 0.0f);
    float lg = z1 * ws[OFF_WN2 + t];
    float d0 = zd * ws[OFF_WD2 + t * 2 + 0];
    float d1 = zd * ws[OFF_WD2 + t * 2 + 1];
    #pragma unroll
    for (int off = 32; off > 0; off >>= 1) {
        lg += __shfl_xor(lg, off, 64);
        d0 += __shfl_xor(d0, off, 64);
        d1 += __shfl_xor(d1, off, 64);
    }
    if (t == 0) {
        store_out(out, i,              lg + ws[OFF_BN2],     bf);
        store_out(out, NN + i * 2 + 0, d0 + ws[OFF_BD2 + 0], bf);
        store_out(out, NN + i * 2 + 1, d1 + ws[OFF_BD2 + 1], bf);
    }
}

// ---- pooled mean + value head ----
__global__ __launch_bounds__(1024) void k_value(float* ws, const unsigned* nf, void* out) {
    bool bf = detect_bf(nf);
    __shared__ float part[8 * HID];
    __shared__ float pooled[HID];
    int t = threadIdx.x;
    int g = t >> 7, c = t & 127;
    float s = 0.0f;
    for (int r = 0; r < 128; r++) s += ws[OFF_H + (g * 128 + r) * HID + c];
    part[g * HID + c] = s;
    __syncthreads();
    if (t < HID) {
        float p = 0.0f;
        #pragma unroll
        for (int gg = 0; gg < 8; gg++) p += part[gg * HID + t];
        pooled[t] = p * (1.0f / NN);
    }
    __syncthreads();
    if (t < 64) {
        float z = ws[OFF_BV1 + t];
        for (int k = 0; k < HID; k++) z += pooled[k] * ws[OFF_WV1 + k * 64 + t];
        z = fmaxf(z, 0.0f);
        float pv = z * ws[OFF_WV2 + t];
        #pragma unroll
        for (int off = 32; off > 0; off >>= 1) pv += __shfl_xor(pv, off, 64);
        if (t == 0) store_out(out, 3072, pv + ws[OFF_BV2], bf);
    }
}

extern "C" void kernel_launch(void* const* d_in, const int* in_sizes, int n_in,
                              void* d_out, int out_size, void* d_ws, size_t ws_size,
                              hipStream_t stream) {
    float* ws = (float*)d_ws;
    const unsigned* nf = (const unsigned*)d_in[0];

    P21 ptrs;
    const int map[21] = {0,2,3,4,5,6,7,8,9,10,11,12,13,14,15,16,17,18,19,20,21};
    for (int s = 0; s < 21; s++) ptrs.p[s] = d_in[map[s]];
    k_convert<<<(CONV_TOTAL + 255) / 256, 256, 0, stream>>>(ptrs, nf, ws);

    k_mask<<<NN, 1024, 0, stream>>>(d_in[1], nf, ws);
    k_h0<<<NN, 128, 0, stream>>>(ws);

    for (int l = 0; l < NL; l++) {
        k_mm3<<<dim3(NN / 4, 3), 128, 0, stream>>>(ws, l);
        k_attn<<<NN, 256, 0, stream>>>(ws, l);
    }

    k_heads<<<NN, 64, 0, stream>>>(ws, nf, d_out);
    k_value<<<1, 1024, 0, stream>>>(ws, nf, d_out);
}

// Round 3
// 278.892 us; speedup vs baseline: 3.6546x; 1.9315x over previous
//
#include <hip/hip_runtime.h>
#include <hip/hip_bf16.h>

#define NN 1024
#define HID 128
#define NHEADS 4
#define HDD 32
#define NL 3

// ---- ws layout (float-word units) ----
constexpr int OFF_CONV = 16;
constexpr int OFF_NF   = OFF_CONV;            // 3072
constexpr int OFF_WP   = OFF_NF  + 3072;      // 384
constexpr int OFF_BP   = OFF_WP  + 384;       // 128
constexpr int OFF_WL   = OFF_BP  + 128;       // 49152
constexpr int OFF_WR   = OFF_WL  + 49152;     // 49152
constexpr int OFF_WVW  = OFF_WR  + 49152;     // 49152
constexpr int OFF_ATT  = OFF_WVW + 49152;     // 96
constexpr int OFF_GAM  = OFF_ATT + 96;        // 384
constexpr int OFF_BET  = OFF_GAM + 384;       // 384
constexpr int OFF_WN1  = OFF_BET + 384;       // 8192
constexpr int OFF_BN1  = OFF_WN1 + 8192;      // 64
constexpr int OFF_WN2  = OFF_BN1 + 64;        // 64
constexpr int OFF_BN2  = OFF_WN2 + 64;        // 1
constexpr int OFF_WD1  = OFF_BN2 + 1;         // 8192
constexpr int OFF_BD1  = OFF_WD1 + 8192;      // 64
constexpr int OFF_WD2  = OFF_BD1 + 64;        // 128
constexpr int OFF_BD2  = OFF_WD2 + 128;       // 2
constexpr int OFF_WV1  = OFF_BD2 + 2;         // 8192
constexpr int OFF_BV1  = OFF_WV1 + 8192;      // 64
constexpr int OFF_WV2  = OFF_BV1 + 64;        // 64
constexpr int OFF_BV2  = OFF_WV2 + 64;        // 1
constexpr int OFF_CONV_END = OFF_BV2 + 1;
constexpr int CONV_TOTAL = OFF_CONV_END - OFF_CONV;
constexpr int OFF_MASK = 176960;              // 1024*32 uint32 words
constexpr int OFF_H    = OFF_MASK + NN*32;
constexpr int OFF_WLH  = OFF_H   + NN*HID;    // normal [i][128]
constexpr int OFF_WRH  = OFF_WLH + NN*HID;    // TRANSPOSED [dq=32][j=1024][4]
constexpr int OFF_WVH  = OFF_WRH + NN*HID;    // TRANSPOSED [dq=32][j=1024][4]
constexpr int OFF_CL   = OFF_WVH + NN*HID;    // [h][i]  0.6*att.wl
constexpr int OFF_CR   = OFF_CL  + NHEADS*NN; // [h][j]  0.6*att.wr

__device__ __forceinline__ float bf2f(unsigned short u) {
    return __uint_as_float(((unsigned)u) << 16);
}
__device__ __forceinline__ void store_out(void* out, int idx, float v, bool bf) {
    if (bf) {
        unsigned u = __float_as_uint(v);
        unsigned r = (u + 0x7FFFu + ((u >> 16) & 1u)) >> 16;
        ((unsigned short*)out)[idx] = (unsigned short)r;
    } else {
        ((float*)out)[idx] = v;
    }
}
// per-wave dtype sniff: fp32 normals have exponent field in [110,140];
// packed bf16 pairs viewed as fp32 essentially never do. Call from ALL lanes.
__device__ __forceinline__ bool detect_bf(const unsigned* nf) {
    unsigned w = nf[threadIdx.x & 63];
    int e = (int)((w >> 23) & 0xFFu);
    unsigned long long b = __ballot(e >= 110 && e <= 140);
    return __popcll(b) < 32;
}

// ---- convert all non-adj params to fp32 in ws ----
struct P21 { const void* p[21]; };
__device__ const int g_sizes[21] = {3072,384,128,49152,49152,49152,96,384,384,
                                    8192,64,64,1,8192,64,128,2,8192,64,64,1};
__device__ const int g_dsts[21] = {OFF_NF,OFF_WP,OFF_BP,OFF_WL,OFF_WR,OFF_WVW,OFF_ATT,
                                   OFF_GAM,OFF_BET,OFF_WN1,OFF_BN1,OFF_WN2,OFF_BN2,
                                   OFF_WD1,OFF_BD1,OFF_WD2,OFF_BD2,OFF_WV1,OFF_BV1,
                                   OFF_WV2,OFF_BV2};
__global__ __launch_bounds__(256) void k_convert(P21 in, const unsigned* nf, float* ws) {
    bool bf = detect_bf(nf);
    int g = blockIdx.x * blockDim.x + threadIdx.x;
    if (g >= CONV_TOTAL) return;
    int rem = g, s = 0;
    while (s < 21 && rem >= g_sizes[s]) { rem -= g_sizes[s]; s++; }
    if (s >= 21) return;
    float v;
    if (bf) v = bf2f(((const unsigned short*)in.p[s])[rem]);
    else    v = ((const float*)in.p[s])[rem];
    ws[g_dsts[s] + rem] = v;
}

// ---- adj -> packed bitmask ----
__global__ __launch_bounds__(1024) void k_mask(const void* adj, const unsigned* nf, float* ws) {
    bool bf = detect_bf(nf);
    unsigned* mask = (unsigned*)(ws + OFF_MASK);
    int i = blockIdx.x, t = threadIdx.x;
    float v = bf ? bf2f(((const unsigned short*)adj)[i * NN + t])
                 : ((const float*)adj)[i * NN + t];
    unsigned long long b = __ballot(v > 0.5f);
    int lane = t & 63, wv = t >> 6;
    if (lane == 0) {
        mask[i * 32 + wv * 2]     = (unsigned)b;
        mask[i * 32 + wv * 2 + 1] = (unsigned)(b >> 32);
    }
}

// ---- h0 = relu(nf @ Wp + bp) ----
__global__ __launch_bounds__(128) void k_h0(float* ws) {
    int i = blockIdx.x, c = threadIdx.x;
    const float* nf = ws + OFF_NF;
    const float* Wp = ws + OFF_WP;
    float a = ws[OFF_BP + c];
    #pragma unroll
    for (int k = 0; k < 3; k++) a += nf[i * 3 + k] * Wp[k * HID + c];
    ws[OFF_H + i * HID + c] = fmaxf(a, 0.0f);
}

// ---- per layer: wlh = h@Wl (normal + cl), wrh/wvh = h@{Wr,Wv} (transposed + cr) ----
__global__ __launch_bounds__(128) void k_mm3(float* ws, int l) {
    __shared__ float hs[4][HID];
    int c = threadIdx.x, i0 = blockIdx.x * 4, which = blockIdx.y;
    const float* h = ws + OFF_H;
    #pragma unroll
    for (int r = 0; r < 4; r++) hs[r][c] = h[(i0 + r) * HID + c];
    __syncthreads();
    int woff = (which == 0) ? OFF_WL : (which == 1) ? OFF_WR : OFF_WVW;
    const float* W = ws + woff + l * HID * HID;
    float a[4] = {0,0,0,0};
    #pragma unroll 4
    for (int k = 0; k < HID; k++) {
        float w = W[k * HID + c];
        #pragma unroll
        for (int r = 0; r < 4; r++) a[r] += hs[r][k] * w;
    }
    if (which == 0) {
        #pragma unroll
        for (int r = 0; r < 4; r++) ws[OFF_WLH + (i0 + r) * HID + c] = a[r];
        float att = ws[OFF_ATT + l * HDD + (c & 31)];
        #pragma unroll
        for (int r = 0; r < 4; r++) {
            float t = att * a[r];
            #pragma unroll
            for (int off = 1; off < 32; off <<= 1) t += __shfl_xor(t, off, 64);
            if ((c & 31) == 0) ws[OFF_CL + (c >> 5) * NN + (i0 + r)] = 0.6f * t;
        }
    } else {
        int doff = (which == 1) ? OFF_WRH : OFF_WVH;
        // transposed-tiled: element (j, c) -> [c>>2][j][c&3]
        #pragma unroll
        for (int r = 0; r < 4; r++)
            ws[doff + (c >> 2) * (NN * 4) + (i0 + r) * 4 + (c & 3)] = a[r];
        if (which == 1) {
            float att = ws[OFF_ATT + l * HDD + (c & 31)];
            #pragma unroll
            for (int r = 0; r < 4; r++) {
                float t = att * a[r];
                #pragma unroll
                for (int off = 1; off < 32; off <<= 1) t += __shfl_xor(t, off, 64);
                if ((c & 31) == 0) ws[OFF_CR + (c >> 5) * NN + (i0 + r)] = 0.6f * t;
            }
        }
    }
}

// ---- per layer: fused attention, lane-per-j, coalesced transposed operands ----
// block = 256 threads = 4 waves; wave w = head w; one block per node i.
// e_ij = 0.6*att.(wl_i+wr_j) + sum_d 0.4*att_d*|wl_id + wr_jd|   (exact leaky split)
//
// Register-pressure design (the r1/r2 lesson): fully-unrolled jc loops with
// unconditional global loads let LLVM hoist many iterations' float4 dests ->
// >256 live regs -> 58 MB/dispatch scratch spill. So: (a) e[16] lives in LDS,
// not registers (frees att_r/wl_r after pass 1 too); (b) #pragma unroll 1 on
// both jc loops caps in-flight loads at 8 float4; (c) inner d-loops stay
// unrolled (static indexing only).
__global__ __launch_bounds__(256) void k_attn(float* ws, int l) {
    int i = blockIdx.x, t = threadIdx.x;
    int lane = t & 63;
    int h = __builtin_amdgcn_readfirstlane(t >> 6);
    __shared__ unsigned mrow[32];
    // buf: per-wave-private [64][33] region. Cols 0..15 hold masked e_j during
    // passes 1-2 (addr lane*33+jc -> (lane+jc)%32 banks, conflict-free);
    // afterwards the full 33-wide row holds acc[] for the cross-lane reduce.
    __shared__ float buf[4][64][33];
    __shared__ float invs[4];
    __shared__ float agg_s[HID];
    __shared__ float red[4];
    const unsigned* mask = (const unsigned*)(ws + OFF_MASK);
    if (t < 32) mrow[t] = mask[i * 32 + t];
    __syncthreads();

    // per-lane 16-bit mask: bit jc = adjacency of j = jc*64+lane
    unsigned mbits = 0;
    #pragma unroll
    for (int jc = 0; jc < 16; jc++)
        mbits |= ((mrow[jc * 2 + (lane >> 5)] >> (lane & 31)) & 1u) << jc;

    // wave-uniform vectors -> registers (0.4 folded into att)
    float att_r[32], wl_r[32];
    const float* attp = ws + OFF_ATT + l * HDD;
    const float* wlp  = ws + OFF_WLH + i * HID + h * HDD;
    #pragma unroll
    for (int d = 0; d < 32; d++) { att_r[d] = 0.4f * attp[d]; wl_r[d] = wlp[d]; }
    float cl6 = ws[OFF_CL + h * NN + i];

    const float* wrT = ws + OFF_WRH + h * 8 * (NN * 4) + lane * 4;
    const float* wvT = ws + OFF_WVH + h * 8 * (NN * 4) + lane * 4;
    const float* crp = ws + OFF_CR + h * NN;

    // pass 1: e_j per lane -> LDS, track lane max
    float m = -1e30f;
    #pragma unroll 1
    for (int jc = 0; jc < 16; jc++) {
        float cr6 = crp[jc * 64 + lane];
        float dot = 0.0f;
        #pragma unroll
        for (int dq = 0; dq < 8; dq++) {
            float4 w = *(const float4*)(wrT + dq * (NN * 4) + jc * 256);
            dot = fmaf(att_r[dq*4+0], fabsf(wl_r[dq*4+0] + w.x), dot);
            dot = fmaf(att_r[dq*4+1], fabsf(wl_r[dq*4+1] + w.y), dot);
            dot = fmaf(att_r[dq*4+2], fabsf(wl_r[dq*4+2] + w.z), dot);
            dot = fmaf(att_r[dq*4+3], fabsf(wl_r[dq*4+3] + w.w), dot);
        }
        float ej = (cl6 + cr6) + dot;
        ej = ((mbits >> jc) & 1u) ? ej : -1e9f;
        buf[h][lane][jc] = ej;
        m = fmaxf(m, ej);
    }
    #pragma unroll
    for (int off = 32; off > 0; off >>= 1) m = fmaxf(m, __shfl_xor(m, off, 64));

    // pass 2: pe = exp(e - m) (masked -> exact 0), accumulate pe * v
    float acc[32];
    #pragma unroll
    for (int d = 0; d < 32; d++) acc[d] = 0.0f;
    float lsum = 0.0f;
    #pragma unroll 1
    for (int jc = 0; jc < 16; jc++) {
        float pe = __expf(buf[h][lane][jc] - m);
        lsum += pe;
        #pragma unroll
        for (int dq = 0; dq < 8; dq++) {
            float4 v = *(const float4*)(wvT + dq * (NN * 4) + jc * 256);
            acc[dq*4+0] = fmaf(pe, v.x, acc[dq*4+0]);
            acc[dq*4+1] = fmaf(pe, v.y, acc[dq*4+1]);
            acc[dq*4+2] = fmaf(pe, v.z, acc[dq*4+2]);
            acc[dq*4+3] = fmaf(pe, v.w, acc[dq*4+3]);
        }
    }
    #pragma unroll
    for (int off = 32; off > 0; off >>= 1) lsum += __shfl_xor(lsum, off, 64);
    if (lane == 0) invs[h] = 1.0f / lsum;
    #pragma unroll
    for (int d = 0; d < 32; d++) buf[h][lane][d] = acc[d];
    __syncthreads();

    // cross-lane reduce via LDS: thread t -> (head, d, lane-half)
    {
        int h2 = t >> 6, idx = t & 63, d = idx & 31, half = idx >> 5;
        float s = 0.0f;
        #pragma unroll
        for (int lq = 0; lq < 32; lq++) s += buf[h2][half * 32 + lq][d];
        s += __shfl_xor(s, 32, 64);
        if (half == 0) agg_s[h2 * 32 + d] = s * invs[h2];
    }
    __syncthreads();

    // layernorm over 128 features + residual, threads 0..127
    float s = 0.f, s2 = 0.f, agg = 0.f;
    if (t < HID) {
        agg = agg_s[t];
        s = agg; s2 = agg * agg;
        #pragma unroll
        for (int off = 32; off > 0; off >>= 1) {
            s  += __shfl_xor(s,  off, 64);
            s2 += __shfl_xor(s2, off, 64);
        }
        if ((t & 63) == 0) { red[(t >> 6) * 2] = s; red[(t >> 6) * 2 + 1] = s2; }
    }
    __syncthreads();
    if (t < HID) {
        float ts = red[0] + red[2], ts2 = red[1] + red[3];
        float mu  = ts  * (1.0f / HID);
        float var = ts2 * (1.0f / HID) - mu * mu;
        float g  = ws[OFF_GAM + l * HID + t];
        float be = ws[OFF_BET + l * HID + t];
        float o = (agg - mu) * rsqrtf(var + 1e-5f) * g + be;
        ws[OFF_H + i * HID + t] += fmaxf(o, 0.0f);
    }
}

// ---- node_logits + delta_mu heads ----
__global__ __launch_bounds__(64) void k_heads(float* ws, const unsigned* nf, void* out) {
    bool bf = detect_bf(nf);
    int i = blockIdx.x, t = threadIdx.x;
    __shared__ float hrow[HID];
    hrow[t]      = ws[OFF_H + i * HID + t];
    hrow[t + 64] = ws[OFF_H + i * HID + t + 64];
    __syncthreads();
    const float* Wn1 = ws + OFF_WN1;
    const float* Wd1 = ws + OFF_WD1;
    float z1 = ws[OFF_BN1 + t], zd = ws[OFF_BD1 + t];
    #pragma unroll 4
    for (int k = 0; k < HID; k++) {
        float hk = hrow[k];
        z1 += hk * Wn1[k * 64 + t];
        zd += hk * Wd1[k * 64 + t];
    }
    z1 = fmaxf(z1, 0.0f); zd = fmaxf(zd, 0.0f);
    float lg = z1 * ws[OFF_WN2 + t];
    float d0 = zd * ws[OFF_WD2 + t * 2 + 0];
    float d1 = zd * ws[OFF_WD2 + t * 2 + 1];
    #pragma unroll
    for (int off = 32; off > 0; off >>= 1) {
        lg += __shfl_xor(lg, off, 64);
        d0 += __shfl_xor(d0, off, 64);
        d1 += __shfl_xor(d1, off, 64);
    }
    if (t == 0) {
        store_out(out, i,              lg + ws[OFF_BN2],     bf);
        store_out(out, NN + i * 2 + 0, d0 + ws[OFF_BD2 + 0], bf);
        store_out(out, NN + i * 2 + 1, d1 + ws[OFF_BD2 + 1], bf);
    }
}

// ---- pooled mean + value head ----
__global__ __launch_bounds__(1024) void k_value(float* ws, const unsigned* nf, void* out) {
    bool bf = detect_bf(nf);
    __shared__ float part[8 * HID];
    __shared__ float pooled[HID];
    int t = threadIdx.x;
    int g = t >> 7, c = t & 127;
    float s = 0.0f;
    for (int r = 0; r < 128; r++) s += ws[OFF_H + (g * 128 + r) * HID + c];
    part[g * HID + c] = s;
    __syncthreads();
    if (t < HID) {
        float p = 0.0f;
        #pragma unroll
        for (int gg = 0; gg < 8; gg++) p += part[gg * HID + t];
        pooled[t] = p * (1.0f / NN);
    }
    __syncthreads();
    if (t < 64) {
        float z = ws[OFF_BV1 + t];
        for (int k = 0; k < HID; k++) z += pooled[k] * ws[OFF_WV1 + k * 64 + t];
        z = fmaxf(z, 0.0f);
        float pv = z * ws[OFF_WV2 + t];
        #pragma unroll
        for (int off = 32; off > 0; off >>= 1) pv += __shfl_xor(pv, off, 64);
        if (t == 0) store_out(out, 3072, pv + ws[OFF_BV2], bf);
    }
}

extern "C" void kernel_launch(void* const* d_in, const int* in_sizes, int n_in,
                              void* d_out, int out_size, void* d_ws, size_t ws_size,
                              hipStream_t stream) {
    float* ws = (float*)d_ws;
    const unsigned* nf = (const unsigned*)d_in[0];

    P21 ptrs;
    const int map[21] = {0,2,3,4,5,6,7,8,9,10,11,12,13,14,15,16,17,18,19,20,21};
    for (int s = 0; s < 21; s++) ptrs.p[s] = d_in[map[s]];
    k_convert<<<(CONV_TOTAL + 255) / 256, 256, 0, stream>>>(ptrs, nf, ws);

    k_mask<<<NN, 1024, 0, stream>>>(d_in[1], nf, ws);
    k_h0<<<NN, 128, 0, stream>>>(ws);

    for (int l = 0; l < NL; l++) {
        k_mm3<<<dim3(NN / 4, 3), 128, 0, stream>>>(ws, l);
        k_attn<<<NN, 256, 0, stream>>>(ws, l);
    }

    k_heads<<<NN, 64, 0, stream>>>(ws, nf, d_out);
    k_value<<<1, 1024, 0, stream>>>(ws, nf, d_out);
}

// Round 4
// 255.635 us; speedup vs baseline: 3.9870x; 1.0910x over previous
//
#include <hip/hip_runtime.h>
#include <hip/hip_bf16.h>

#define NN 1024
#define HID 128
#define NHEADS 4
#define HDD 32
#define NL 3

// ---- ws layout (float-word units) ----
constexpr int OFF_CONV = 16;
constexpr int OFF_NF   = OFF_CONV;            // 3072
constexpr int OFF_WP   = OFF_NF  + 3072;      // 384
constexpr int OFF_BP   = OFF_WP  + 384;       // 128
constexpr int OFF_WL   = OFF_BP  + 128;       // 49152
constexpr int OFF_WR   = OFF_WL  + 49152;     // 49152
constexpr int OFF_WVW  = OFF_WR  + 49152;     // 49152
constexpr int OFF_ATT  = OFF_WVW + 49152;     // 96
constexpr int OFF_GAM  = OFF_ATT + 96;        // 384
constexpr int OFF_BET  = OFF_GAM + 384;       // 384
constexpr int OFF_WN1  = OFF_BET + 384;       // 8192
constexpr int OFF_BN1  = OFF_WN1 + 8192;      // 64
constexpr int OFF_WN2  = OFF_BN1 + 64;        // 64
constexpr int OFF_BN2  = OFF_WN2 + 64;        // 1
constexpr int OFF_WD1  = OFF_BN2 + 1;         // 8192
constexpr int OFF_BD1  = OFF_WD1 + 8192;      // 64
constexpr int OFF_WD2  = OFF_BD1 + 64;        // 128
constexpr int OFF_BD2  = OFF_WD2 + 128;       // 2
constexpr int OFF_WV1  = OFF_BD2 + 2;         // 8192
constexpr int OFF_BV1  = OFF_WV1 + 8192;      // 64
constexpr int OFF_WV2  = OFF_BV1 + 64;        // 64
constexpr int OFF_BV2  = OFF_WV2 + 64;        // 1
constexpr int OFF_CONV_END = OFF_BV2 + 1;
constexpr int CONV_TOTAL = OFF_CONV_END - OFF_CONV;
constexpr int CB = (CONV_TOTAL + 255) / 256;  // convert blocks in k_pre
constexpr int OFF_MASK = 176960;              // 1024*32 uint32 words
constexpr int OFF_H    = OFF_MASK + NN*32;
constexpr int OFF_WLH  = OFF_H   + NN*HID;    // normal [i][128]
constexpr int OFF_WRH  = OFF_WLH + NN*HID;    // TRANSPOSED [dq=32][j=1024][4]
constexpr int OFF_WVH  = OFF_WRH + NN*HID;    // TRANSPOSED [dq=32][j=1024][4]
constexpr int OFF_CL   = OFF_WVH + NN*HID;    // [h][i]  0.6*att.wl
constexpr int OFF_CR   = OFF_CL  + NHEADS*NN; // [h][j]  0.6*att.wr

__device__ __forceinline__ float bf2f(unsigned short u) {
    return __uint_as_float(((unsigned)u) << 16);
}
__device__ __forceinline__ void store_out(void* out, int idx, float v, bool bf) {
    if (bf) {
        unsigned u = __float_as_uint(v);
        unsigned r = (u + 0x7FFFu + ((u >> 16) & 1u)) >> 16;
        ((unsigned short*)out)[idx] = (unsigned short)r;
    } else {
        ((float*)out)[idx] = v;
    }
}
__device__ __forceinline__ float ldraw(const void* p, int idx, bool bf) {
    return bf ? bf2f(((const unsigned short*)p)[idx]) : ((const float*)p)[idx];
}
// per-wave dtype sniff: fp32 normals have exponent field in [110,140];
// packed bf16 pairs viewed as fp32 essentially never do. Call from ALL lanes.
__device__ __forceinline__ bool detect_bf(const unsigned* nf) {
    unsigned w = nf[threadIdx.x & 63];
    int e = (int)((w >> 23) & 0xFFu);
    unsigned long long b = __ballot(e >= 110 && e <= 140);
    return __popcll(b) < 32;
}

struct P21 { const void* p[21]; };
__device__ const int g_sizes[21] = {3072,384,128,49152,49152,49152,96,384,384,
                                    8192,64,64,1,8192,64,128,2,8192,64,64,1};
__device__ const int g_dsts[21] = {OFF_NF,OFF_WP,OFF_BP,OFF_WL,OFF_WR,OFF_WVW,OFF_ATT,
                                   OFF_GAM,OFF_BET,OFF_WN1,OFF_BN1,OFF_WN2,OFF_BN2,
                                   OFF_WD1,OFF_BD1,OFF_WD2,OFF_BD2,OFF_WV1,OFF_BV1,
                                   OFF_WV2,OFF_BV2};

// ---- fused prologue: param convert | adj->bitmask | h0  (all independent:
// h0 reads RAW nf/Wp/bp with its own bf16 handling, so no ordering needed) ----
__global__ __launch_bounds__(256) void k_pre(P21 in, const void* adj, const unsigned* nf, float* ws) {
    bool bf = detect_bf(nf);
    int b = blockIdx.x, t = threadIdx.x;
    if (b < CB) {
        // convert all non-adj params to fp32 in ws
        int g = b * 256 + t;
        if (g >= CONV_TOTAL) return;
        int rem = g, s = 0;
        while (s < 21 && rem >= g_sizes[s]) { rem -= g_sizes[s]; s++; }
        if (s >= 21) return;
        ws[g_dsts[s] + rem] = ldraw(in.p[s], rem, bf);
    } else if (b < CB + NN) {
        // adj row -> packed bitmask
        int i = b - CB;
        unsigned* mask = (unsigned*)(ws + OFF_MASK);
        int lane = t & 63, wv = t >> 6;
        #pragma unroll
        for (int q = 0; q < 4; q++) {
            int seg = wv * 4 + q;
            int j = seg * 64 + lane;
            float v = ldraw(adj, i * NN + j, bf);
            unsigned long long bl = __ballot(v > 0.5f);
            if (lane == 0) {
                mask[i * 32 + seg * 2]     = (unsigned)bl;
                mask[i * 32 + seg * 2 + 1] = (unsigned)(bl >> 32);
            }
        }
    } else {
        // h0 = relu(nf @ Wp + bp), raw reads: 2 nodes per block
        int bb = b - CB - NN;
        int i = bb * 2 + (t >> 7), c = t & 127;
        float a = ldraw(in.p[2], c, bf);                     // bp
        #pragma unroll
        for (int k = 0; k < 3; k++)
            a += ldraw(in.p[0], i * 3 + k, bf) * ldraw(in.p[1], k * HID + c, bf);
        ws[OFF_H + i * HID + c] = fmaxf(a, 0.0f);
    }
}

// ---- per layer: wlh = h@Wl (normal + cl), wrh/wvh = h@{Wr,Wv} (transposed + cr) ----
__global__ __launch_bounds__(128) void k_mm3(float* ws, int l) {
    __shared__ float hs[4][HID];
    int c = threadIdx.x, i0 = blockIdx.x * 4, which = blockIdx.y;
    const float* h = ws + OFF_H;
    #pragma unroll
    for (int r = 0; r < 4; r++) hs[r][c] = h[(i0 + r) * HID + c];
    __syncthreads();
    int woff = (which == 0) ? OFF_WL : (which == 1) ? OFF_WR : OFF_WVW;
    const float* W = ws + woff + l * HID * HID;
    float a[4] = {0,0,0,0};
    #pragma unroll 4
    for (int k = 0; k < HID; k++) {
        float w = W[k * HID + c];
        #pragma unroll
        for (int r = 0; r < 4; r++) a[r] += hs[r][k] * w;
    }
    if (which == 0) {
        #pragma unroll
        for (int r = 0; r < 4; r++) ws[OFF_WLH + (i0 + r) * HID + c] = a[r];
        float att = ws[OFF_ATT + l * HDD + (c & 31)];
        #pragma unroll
        for (int r = 0; r < 4; r++) {
            float t = att * a[r];
            #pragma unroll
            for (int off = 1; off < 32; off <<= 1) t += __shfl_xor(t, off, 64);
            if ((c & 31) == 0) ws[OFF_CL + (c >> 5) * NN + (i0 + r)] = 0.6f * t;
        }
    } else {
        int doff = (which == 1) ? OFF_WRH : OFF_WVH;
        // transposed-tiled: element (j, c) -> [c>>2][j][c&3]
        #pragma unroll
        for (int r = 0; r < 4; r++)
            ws[doff + (c >> 2) * (NN * 4) + (i0 + r) * 4 + (c & 3)] = a[r];
        if (which == 1) {
            float att = ws[OFF_ATT + l * HDD + (c & 31)];
            #pragma unroll
            for (int r = 0; r < 4; r++) {
                float t = att * a[r];
                #pragma unroll
                for (int off = 1; off < 32; off <<= 1) t += __shfl_xor(t, off, 64);
                if ((c & 31) == 0) ws[OFF_CR + (c >> 5) * NN + (i0 + r)] = 0.6f * t;
            }
        }
    }
}

// ---- per layer: fused attention, 4-node-tiled ----
// Block = 512 threads = 8 waves, 4 NODES per block (grid 256 = 1 block/CU).
// Wave w: head h = w&3, node-pair p = w>>2 -> nodes iA=i0+2p, iB=iA+1.
// Each streamed wr_j/wv_j element is used for 2 nodes -> L2 traffic/dispatch
// drops 1 GB -> 256 MB vs the 1-node/block version (which ran at 22 TB/s L2,
// 65% of ceiling).
// e_ij = 0.6*att.(wl_i+wr_j) + sum_d 0.4*att_d*|wl_id + wr_jd|  (exact leaky split)
// Register discipline (r1/r2 lesson): unroll-1 jc loops; e (both nodes) in LDS
// stride-33 (conflict-free); peak live ~ att32+wl64+inflight32 -> ~<220 VGPR.
__global__ __launch_bounds__(512) void k_attn(float* ws, int l) {
    int t = threadIdx.x;
    int i0 = blockIdx.x * 4;
    int lane = t & 63;
    int w = t >> 6;
    int h = __builtin_amdgcn_readfirstlane(w & 3);
    int p = __builtin_amdgcn_readfirstlane(w >> 2);
    int iA = i0 + 2 * p, iB = iA + 1;

    __shared__ unsigned mrow[4][32];
    __shared__ float ebuf[8][64][33];   // 67.6 KB: e-store, then acc-reduce scratch
    __shared__ float invs[4][4];        // [node][head]
    __shared__ float agg_s[4][HID];
    __shared__ float red2[4][2][2];

    if (t < 128) mrow[t >> 5][t & 31] = ((const unsigned*)(ws + OFF_MASK))[i0 * 32 + t];
    __syncthreads();

    // per-lane 16-bit adjacency masks for both nodes: bit jc = adj of j=jc*64+lane
    unsigned mbA = 0, mbB = 0;
    #pragma unroll
    for (int jc = 0; jc < 16; jc++) {
        int wi = jc * 2 + (lane >> 5);
        mbA |= ((mrow[2 * p][wi] >> (lane & 31)) & 1u) << jc;
        mbB |= ((mrow[2 * p + 1][wi] >> (lane & 31)) & 1u) << jc;
    }

    // wave-uniform vectors -> registers (0.4 folded into att)
    float att_r[32], wlA[32], wlB[32];
    const float* attp = ws + OFF_ATT + l * HDD;
    const float* wlpA = ws + OFF_WLH + iA * HID + h * HDD;
    const float* wlpB = ws + OFF_WLH + iB * HID + h * HDD;
    #pragma unroll
    for (int d = 0; d < 32; d++) {
        att_r[d] = 0.4f * attp[d];
        wlA[d] = wlpA[d];
        wlB[d] = wlpB[d];
    }
    float clA = ws[OFF_CL + h * NN + iA];
    float clB = ws[OFF_CL + h * NN + iB];

    const float* wrT = ws + OFF_WRH + h * 8 * (NN * 4) + lane * 4;
    const float* wvT = ws + OFF_WVH + h * 8 * (NN * 4) + lane * 4;
    const float* crp = ws + OFF_CR + h * NN;

    // pass 1: e for both nodes -> LDS, track lane maxes
    float mA = -1e30f, mB = -1e30f;
    #pragma unroll 1
    for (int jc = 0; jc < 16; jc++) {
        float cr6 = crp[jc * 64 + lane];
        float dA = 0.0f, dB = 0.0f;
        #pragma unroll
        for (int dq = 0; dq < 8; dq++) {
            float4 wv4 = *(const float4*)(wrT + dq * (NN * 4) + jc * 256);
            dA = fmaf(att_r[dq*4+0], fabsf(wlA[dq*4+0] + wv4.x), dA);
            dB = fmaf(att_r[dq*4+0], fabsf(wlB[dq*4+0] + wv4.x), dB);
            dA = fmaf(att_r[dq*4+1], fabsf(wlA[dq*4+1] + wv4.y), dA);
            dB = fmaf(att_r[dq*4+1], fabsf(wlB[dq*4+1] + wv4.y), dB);
            dA = fmaf(att_r[dq*4+2], fabsf(wlA[dq*4+2] + wv4.z), dA);
            dB = fmaf(att_r[dq*4+2], fabsf(wlB[dq*4+2] + wv4.z), dB);
            dA = fmaf(att_r[dq*4+3], fabsf(wlA[dq*4+3] + wv4.w), dA);
            dB = fmaf(att_r[dq*4+3], fabsf(wlB[dq*4+3] + wv4.w), dB);
        }
        float eA = (clA + cr6) + dA; eA = ((mbA >> jc) & 1u) ? eA : -1e9f;
        float eB = (clB + cr6) + dB; eB = ((mbB >> jc) & 1u) ? eB : -1e9f;
        ebuf[w][lane][jc]      = eA;
        ebuf[w][lane][16 + jc] = eB;
        mA = fmaxf(mA, eA);
        mB = fmaxf(mB, eB);
    }
    #pragma unroll
    for (int off = 32; off > 0; off >>= 1) {
        mA = fmaxf(mA, __shfl_xor(mA, off, 64));
        mB = fmaxf(mB, __shfl_xor(mB, off, 64));
    }

    // pass 2: pe = exp(e - m) (masked -> exact 0), accumulate pe * v for both nodes
    float accA[32], accB[32];
    #pragma unroll
    for (int d = 0; d < 32; d++) { accA[d] = 0.0f; accB[d] = 0.0f; }
    float lsA = 0.0f, lsB = 0.0f;
    #pragma unroll 1
    for (int jc = 0; jc < 16; jc++) {
        float peA = __expf(ebuf[w][lane][jc]      - mA);
        float peB = __expf(ebuf[w][lane][16 + jc] - mB);
        lsA += peA; lsB += peB;
        #pragma unroll
        for (int dq = 0; dq < 8; dq++) {
            float4 v4 = *(const float4*)(wvT + dq * (NN * 4) + jc * 256);
            accA[dq*4+0] = fmaf(peA, v4.x, accA[dq*4+0]);
            accB[dq*4+0] = fmaf(peB, v4.x, accB[dq*4+0]);
            accA[dq*4+1] = fmaf(peA, v4.y, accA[dq*4+1]);
            accB[dq*4+1] = fmaf(peB, v4.y, accB[dq*4+1]);
            accA[dq*4+2] = fmaf(peA, v4.z, accA[dq*4+2]);
            accB[dq*4+2] = fmaf(peB, v4.z, accB[dq*4+2]);
            accA[dq*4+3] = fmaf(peA, v4.w, accA[dq*4+3]);
            accB[dq*4+3] = fmaf(peB, v4.w, accB[dq*4+3]);
        }
    }
    #pragma unroll
    for (int off = 32; off > 0; off >>= 1) {
        lsA += __shfl_xor(lsA, off, 64);
        lsB += __shfl_xor(lsB, off, 64);
    }
    if (lane == 0) {
        invs[2 * p][h]     = 1.0f / lsA;
        invs[2 * p + 1][h] = 1.0f / lsB;
    }
    __syncthreads();   // all e-reads done; ebuf reusable; invs visible

    // acc cross-lane reduce via LDS, 2 rounds (node = 2p + r); region = p*4+h
    float* rbuf = &ebuf[0][0][0];
    {   // round r=0: node iA
        int reg = p * 4 + h;
        #pragma unroll
        for (int d = 0; d < 32; d++) rbuf[(reg * 64 + lane) * 33 + d] = accA[d];
        __syncthreads();
        int g = t >> 6, d = lane & 31, half = lane >> 5;
        float s = 0.0f;
        #pragma unroll
        for (int lq = 0; lq < 32; lq++) s += rbuf[(g * 64 + half * 32 + lq) * 33 + d];
        s += __shfl_xor(s, 32, 64);
        int node = 2 * (g >> 2), hh = g & 3;
        if (half == 0) agg_s[node][hh * 32 + d] = s * invs[node][hh];
        __syncthreads();
    }
    {   // round r=1: node iB
        int reg = p * 4 + h;
        #pragma unroll
        for (int d = 0; d < 32; d++) rbuf[(reg * 64 + lane) * 33 + d] = accB[d];
        __syncthreads();
        int g = t >> 6, d = lane & 31, half = lane >> 5;
        float s = 0.0f;
        #pragma unroll
        for (int lq = 0; lq < 32; lq++) s += rbuf[(g * 64 + half * 32 + lq) * 33 + d];
        s += __shfl_xor(s, 32, 64);
        int node = 2 * (g >> 2) + 1, hh = g & 3;
        if (half == 0) agg_s[node][hh * 32 + d] = s * invs[node][hh];
        __syncthreads();
    }

    // layernorm + residual for the 4 nodes: t -> node n=t>>7, feature f=t&127
    {
        int n = t >> 7, f = t & 127;
        float agg = agg_s[n][f];
        float s = agg, s2 = agg * agg;
        #pragma unroll
        for (int off = 32; off > 0; off >>= 1) {
            s  += __shfl_xor(s,  off, 64);
            s2 += __shfl_xor(s2, off, 64);
        }
        int half = (t >> 6) & 1;
        if (lane == 0) { red2[n][half][0] = s; red2[n][half][1] = s2; }
        __syncthreads();
        float ts  = red2[n][0][0] + red2[n][1][0];
        float ts2 = red2[n][0][1] + red2[n][1][1];
        float mu  = ts  * (1.0f / HID);
        float var = ts2 * (1.0f / HID) - mu * mu;
        float gm = ws[OFF_GAM + l * HID + f];
        float be = ws[OFF_BET + l * HID + f];
        float o = (agg - mu) * rsqrtf(var + 1e-5f) * gm + be;
        ws[OFF_H + (i0 + n) * HID + f] += fmaxf(o, 0.0f);
    }
}

// ---- fused epilogue: node_logits + delta_mu heads (blocks 0..255, 4 nodes each)
//      + pooled mean + value head (block 256) ----
__global__ __launch_bounds__(256) void k_post(float* ws, const unsigned* nf, void* out) {
    bool bf = detect_bf(nf);
    int b = blockIdx.x, t = threadIdx.x;
    if (b < 256) {
        __shared__ float hrow[4][HID];
        int n = t >> 6, tt = t & 63;
        int i = b * 4 + n;
        hrow[n][tt]      = ws[OFF_H + i * HID + tt];
        hrow[n][tt + 64] = ws[OFF_H + i * HID + tt + 64];
        __syncthreads();
        const float* Wn1 = ws + OFF_WN1;
        const float* Wd1 = ws + OFF_WD1;
        float z1 = ws[OFF_BN1 + tt], zd = ws[OFF_BD1 + tt];
        #pragma unroll 4
        for (int k = 0; k < HID; k++) {
            float hk = hrow[n][k];
            z1 += hk * Wn1[k * 64 + tt];
            zd += hk * Wd1[k * 64 + tt];
        }
        z1 = fmaxf(z1, 0.0f); zd = fmaxf(zd, 0.0f);
        float lg = z1 * ws[OFF_WN2 + tt];
        float d0 = zd * ws[OFF_WD2 + tt * 2 + 0];
        float d1 = zd * ws[OFF_WD2 + tt * 2 + 1];
        #pragma unroll
        for (int off = 32; off > 0; off >>= 1) {
            lg += __shfl_xor(lg, off, 64);
            d0 += __shfl_xor(d0, off, 64);
            d1 += __shfl_xor(d1, off, 64);
        }
        if (tt == 0) {
            store_out(out, i,              lg + ws[OFF_BN2],     bf);
            store_out(out, NN + i * 2 + 0, d0 + ws[OFF_BD2 + 0], bf);
            store_out(out, NN + i * 2 + 1, d1 + ws[OFF_BD2 + 1], bf);
        }
    } else {
        __shared__ float part[2][HID];
        __shared__ float pooled[HID];
        int g = t >> 7, c = t & 127;
        float s = 0.0f;
        #pragma unroll 4
        for (int r = g; r < NN; r += 2) s += ws[OFF_H + r * HID + c];
        part[g][c] = s;
        __syncthreads();
        if (t < HID) pooled[t] = (part[0][t] + part[1][t]) * (1.0f / NN);
        __syncthreads();
        if (t < 64) {
            float z = ws[OFF_BV1 + t];
            for (int k = 0; k < HID; k++) z += pooled[k] * ws[OFF_WV1 + k * 64 + t];
            z = fmaxf(z, 0.0f);
            float pv = z * ws[OFF_WV2 + t];
            #pragma unroll
            for (int off = 32; off > 0; off >>= 1) pv += __shfl_xor(pv, off, 64);
            if (t == 0) store_out(out, 3072, pv + ws[OFF_BV2], bf);
        }
    }
}

extern "C" void kernel_launch(void* const* d_in, const int* in_sizes, int n_in,
                              void* d_out, int out_size, void* d_ws, size_t ws_size,
                              hipStream_t stream) {
    float* ws = (float*)d_ws;
    const unsigned* nf = (const unsigned*)d_in[0];

    P21 ptrs;
    const int map[21] = {0,2,3,4,5,6,7,8,9,10,11,12,13,14,15,16,17,18,19,20,21};
    for (int s = 0; s < 21; s++) ptrs.p[s] = d_in[map[s]];

    // prologue: convert (CB blocks) | mask (NN blocks) | h0 (NN/2 blocks)
    k_pre<<<CB + NN + NN / 2, 256, 0, stream>>>(ptrs, d_in[1], nf, ws);

    for (int l = 0; l < NL; l++) {
        k_mm3<<<dim3(NN / 4, 3), 128, 0, stream>>>(ws, l);
        k_attn<<<NN / 4, 512, 0, stream>>>(ws, l);
    }

    k_post<<<257, 256, 0, stream>>>(ws, nf, d_out);
}

// Round 5
// 226.783 us; speedup vs baseline: 4.4943x; 1.1272x over previous
//
#include <hip/hip_runtime.h>
#include <hip/hip_bf16.h>

#define NN 1024
#define HID 128
#define NHEADS 4
#define HDD 32
#define NL 3

// ---- ws layout (float-word units) ----
constexpr int OFF_CONV = 16;
constexpr int OFF_NF   = OFF_CONV;            // 3072
constexpr int OFF_WP   = OFF_NF  + 3072;      // 384
constexpr int OFF_BP   = OFF_WP  + 384;       // 128
constexpr int OFF_WL   = OFF_BP  + 128;       // 49152
constexpr int OFF_WR   = OFF_WL  + 49152;     // 49152
constexpr int OFF_WVW  = OFF_WR  + 49152;     // 49152
constexpr int OFF_ATT  = OFF_WVW + 49152;     // 96
constexpr int OFF_GAM  = OFF_ATT + 96;        // 384
constexpr int OFF_BET  = OFF_GAM + 384;       // 384
constexpr int OFF_WN1  = OFF_BET + 384;       // 8192
constexpr int OFF_BN1  = OFF_WN1 + 8192;      // 64
constexpr int OFF_WN2  = OFF_BN1 + 64;        // 64
constexpr int OFF_BN2  = OFF_WN2 + 64;        // 1
constexpr int OFF_WD1  = OFF_BN2 + 1;         // 8192
constexpr int OFF_BD1  = OFF_WD1 + 8192;      // 64
constexpr int OFF_WD2  = OFF_BD1 + 64;        // 128
constexpr int OFF_BD2  = OFF_WD2 + 128;       // 2
constexpr int OFF_WV1  = OFF_BD2 + 2;         // 8192
constexpr int OFF_BV1  = OFF_WV1 + 8192;      // 64
constexpr int OFF_WV2  = OFF_BV1 + 64;        // 64
constexpr int OFF_BV2  = OFF_WV2 + 64;        // 1
constexpr int OFF_CONV_END = OFF_BV2 + 1;
constexpr int CONV_TOTAL = OFF_CONV_END - OFF_CONV;
constexpr int CB = (CONV_TOTAL + 255) / 256;  // convert blocks in k_pre
constexpr int OFF_MASK = 176960;              // 1024*32 uint32 words
constexpr int OFF_H    = OFF_MASK + NN*32;
constexpr int OFF_WLH  = OFF_H   + NN*HID;    // normal [i][128]
constexpr int OFF_WRH  = OFF_WLH + NN*HID;    // TRANSPOSED [dq=32][j=1024][4]
constexpr int OFF_WVH  = OFF_WRH + NN*HID;    // TRANSPOSED [dq=32][j=1024][4]
constexpr int OFF_CL   = OFF_WVH + NN*HID;    // [h][i]  0.6*att.wl
constexpr int OFF_CR   = OFF_CL  + NHEADS*NN; // [h][j]  0.6*att.wr

__device__ __forceinline__ float bf2f(unsigned short u) {
    return __uint_as_float(((unsigned)u) << 16);
}
__device__ __forceinline__ void store_out(void* out, int idx, float v, bool bf) {
    if (bf) {
        unsigned u = __float_as_uint(v);
        unsigned r = (u + 0x7FFFu + ((u >> 16) & 1u)) >> 16;
        ((unsigned short*)out)[idx] = (unsigned short)r;
    } else {
        ((float*)out)[idx] = v;
    }
}
__device__ __forceinline__ float ldraw(const void* p, int idx, bool bf) {
    return bf ? bf2f(((const unsigned short*)p)[idx]) : ((const float*)p)[idx];
}
// per-wave dtype sniff: fp32 normals have exponent field in [110,140];
// packed bf16 pairs viewed as fp32 essentially never do. Call from ALL lanes.
__device__ __forceinline__ bool detect_bf(const unsigned* nf) {
    unsigned w = nf[threadIdx.x & 63];
    int e = (int)((w >> 23) & 0xFFu);
    unsigned long long b = __ballot(e >= 110 && e <= 140);
    return __popcll(b) < 32;
}

struct P21 { const void* p[21]; };
__device__ const int g_sizes[21] = {3072,384,128,49152,49152,49152,96,384,384,
                                    8192,64,64,1,8192,64,128,2,8192,64,64,1};
__device__ const int g_dsts[21] = {OFF_NF,OFF_WP,OFF_BP,OFF_WL,OFF_WR,OFF_WVW,OFF_ATT,
                                   OFF_GAM,OFF_BET,OFF_WN1,OFF_BN1,OFF_WN2,OFF_BN2,
                                   OFF_WD1,OFF_BD1,OFF_WD2,OFF_BD2,OFF_WV1,OFF_BV1,
                                   OFF_WV2,OFF_BV2};

// ---- fused prologue: param convert | adj->bitmask | h0  (all independent:
// h0 reads RAW nf/Wp/bp with its own bf16 handling, so no ordering needed) ----
__global__ __launch_bounds__(256) void k_pre(P21 in, const void* adj, const unsigned* nf, float* ws) {
    bool bf = detect_bf(nf);
    int b = blockIdx.x, t = threadIdx.x;
    if (b < CB) {
        // convert all non-adj params to fp32 in ws
        int g = b * 256 + t;
        if (g >= CONV_TOTAL) return;
        int rem = g, s = 0;
        while (s < 21 && rem >= g_sizes[s]) { rem -= g_sizes[s]; s++; }
        if (s >= 21) return;
        ws[g_dsts[s] + rem] = ldraw(in.p[s], rem, bf);
    } else if (b < CB + NN) {
        // adj row -> packed bitmask
        int i = b - CB;
        unsigned* mask = (unsigned*)(ws + OFF_MASK);
        int lane = t & 63, wv = t >> 6;
        #pragma unroll
        for (int q = 0; q < 4; q++) {
            int seg = wv * 4 + q;
            int j = seg * 64 + lane;
            float v = ldraw(adj, i * NN + j, bf);
            unsigned long long bl = __ballot(v > 0.5f);
            if (lane == 0) {
                mask[i * 32 + seg * 2]     = (unsigned)bl;
                mask[i * 32 + seg * 2 + 1] = (unsigned)(bl >> 32);
            }
        }
    } else {
        // h0 = relu(nf @ Wp + bp), raw reads: 2 nodes per block
        int bb = b - CB - NN;
        int i = bb * 2 + (t >> 7), c = t & 127;
        float a = ldraw(in.p[2], c, bf);                     // bp
        #pragma unroll
        for (int k = 0; k < 3; k++)
            a += ldraw(in.p[0], i * 3 + k, bf) * ldraw(in.p[1], k * HID + c, bf);
        ws[OFF_H + i * HID + c] = fmaxf(a, 0.0f);
    }
}

// ---- per layer: wlh = h@Wl (normal + cl), wrh/wvh = h@{Wr,Wv} (transposed + cr) ----
__global__ __launch_bounds__(128) void k_mm3(float* ws, int l) {
    __shared__ float hs[4][HID];
    int c = threadIdx.x, i0 = blockIdx.x * 4, which = blockIdx.y;
    const float* h = ws + OFF_H;
    #pragma unroll
    for (int r = 0; r < 4; r++) hs[r][c] = h[(i0 + r) * HID + c];
    __syncthreads();
    int woff = (which == 0) ? OFF_WL : (which == 1) ? OFF_WR : OFF_WVW;
    const float* W = ws + woff + l * HID * HID;
    float a[4] = {0,0,0,0};
    #pragma unroll 4
    for (int k = 0; k < HID; k++) {
        float w = W[k * HID + c];
        #pragma unroll
        for (int r = 0; r < 4; r++) a[r] += hs[r][k] * w;
    }
    if (which == 0) {
        #pragma unroll
        for (int r = 0; r < 4; r++) ws[OFF_WLH + (i0 + r) * HID + c] = a[r];
        float att = ws[OFF_ATT + l * HDD + (c & 31)];
        #pragma unroll
        for (int r = 0; r < 4; r++) {
            float t = att * a[r];
            #pragma unroll
            for (int off = 1; off < 32; off <<= 1) t += __shfl_xor(t, off, 64);
            if ((c & 31) == 0) ws[OFF_CL + (c >> 5) * NN + (i0 + r)] = 0.6f * t;
        }
    } else {
        int doff = (which == 1) ? OFF_WRH : OFF_WVH;
        // transposed-tiled: element (j, c) -> [c>>2][j][c&3]
        #pragma unroll
        for (int r = 0; r < 4; r++)
            ws[doff + (c >> 2) * (NN * 4) + (i0 + r) * 4 + (c & 3)] = a[r];
        if (which == 1) {
            float att = ws[OFF_ATT + l * HDD + (c & 31)];
            #pragma unroll
            for (int r = 0; r < 4; r++) {
                float t = att * a[r];
                #pragma unroll
                for (int off = 1; off < 32; off <<= 1) t += __shfl_xor(t, off, 64);
                if ((c & 31) == 0) ws[OFF_CR + (c >> 5) * NN + (i0 + r)] = 0.6f * t;
            }
        }
    }
}

// ---- per layer: fused attention, 4-node-tiled ----
// Block = 512 threads = 8 waves, 4 NODES per block (grid 256 = 1 block/CU).
// Wave w: head h = w&3, node-pair p = w>>2 -> nodes iA=i0+2p, iB=iA+1.
// Each streamed wr_j/wv_j element is used for 2 nodes -> L2 traffic/dispatch
// drops 1 GB -> 256 MB vs the 1-node/block version (which ran at 22 TB/s L2,
// 65% of ceiling).
// e_ij = 0.6*att.(wl_i+wr_j) + sum_d 0.4*att_d*|wl_id + wr_jd|  (exact leaky split)
// Register discipline (r1/r2 lesson): unroll-1 jc loops; e (both nodes) in LDS
// stride-33 (conflict-free); peak live ~ att32+wl64+inflight32 -> ~<220 VGPR.
__global__ __launch_bounds__(512) void k_attn(float* ws, int l) {
    int t = threadIdx.x;
    int i0 = blockIdx.x * 4;
    int lane = t & 63;
    int w = t >> 6;
    int h = __builtin_amdgcn_readfirstlane(w & 3);
    int p = __builtin_amdgcn_readfirstlane(w >> 2);
    int iA = i0 + 2 * p, iB = iA + 1;

    __shared__ unsigned mrow[4][32];
    __shared__ float ebuf[8][64][33];   // 67.6 KB: e-store, then acc-reduce scratch
    __shared__ float invs[4][4];        // [node][head]
    __shared__ float agg_s[4][HID];
    __shared__ float red2[4][2][2];

    if (t < 128) mrow[t >> 5][t & 31] = ((const unsigned*)(ws + OFF_MASK))[i0 * 32 + t];
    __syncthreads();

    // per-lane 16-bit adjacency masks for both nodes: bit jc = adj of j=jc*64+lane
    unsigned mbA = 0, mbB = 0;
    #pragma unroll
    for (int jc = 0; jc < 16; jc++) {
        int wi = jc * 2 + (lane >> 5);
        mbA |= ((mrow[2 * p][wi] >> (lane & 31)) & 1u) << jc;
        mbB |= ((mrow[2 * p + 1][wi] >> (lane & 31)) & 1u) << jc;
    }

    // wave-uniform vectors -> registers (0.4 folded into att)
    float att_r[32], wlA[32], wlB[32];
    const float* attp = ws + OFF_ATT + l * HDD;
    const float* wlpA = ws + OFF_WLH + iA * HID + h * HDD;
    const float* wlpB = ws + OFF_WLH + iB * HID + h * HDD;
    #pragma unroll
    for (int d = 0; d < 32; d++) {
        att_r[d] = 0.4f * attp[d];
        wlA[d] = wlpA[d];
        wlB[d] = wlpB[d];
    }
    float clA = ws[OFF_CL + h * NN + iA];
    float clB = ws[OFF_CL + h * NN + iB];

    const float* wrT = ws + OFF_WRH + h * 8 * (NN * 4) + lane * 4;
    const float* wvT = ws + OFF_WVH + h * 8 * (NN * 4) + lane * 4;
    const float* crp = ws + OFF_CR + h * NN;

    // pass 1: e for both nodes -> LDS, track lane maxes
    float mA = -1e30f, mB = -1e30f;
    #pragma unroll 1
    for (int jc = 0; jc < 16; jc++) {
        float cr6 = crp[jc * 64 + lane];
        float dA = 0.0f, dB = 0.0f;
        #pragma unroll
        for (int dq = 0; dq < 8; dq++) {
            float4 wv4 = *(const float4*)(wrT + dq * (NN * 4) + jc * 256);
            dA = fmaf(att_r[dq*4+0], fabsf(wlA[dq*4+0] + wv4.x), dA);
            dB = fmaf(att_r[dq*4+0], fabsf(wlB[dq*4+0] + wv4.x), dB);
            dA = fmaf(att_r[dq*4+1], fabsf(wlA[dq*4+1] + wv4.y), dA);
            dB = fmaf(att_r[dq*4+1], fabsf(wlB[dq*4+1] + wv4.y), dB);
            dA = fmaf(att_r[dq*4+2], fabsf(wlA[dq*4+2] + wv4.z), dA);
            dB = fmaf(att_r[dq*4+2], fabsf(wlB[dq*4+2] + wv4.z), dB);
            dA = fmaf(att_r[dq*4+3], fabsf(wlA[dq*4+3] + wv4.w), dA);
            dB = fmaf(att_r[dq*4+3], fabsf(wlB[dq*4+3] + wv4.w), dB);
        }
        float eA = (clA + cr6) + dA; eA = ((mbA >> jc) & 1u) ? eA : -1e9f;
        float eB = (clB + cr6) + dB; eB = ((mbB >> jc) & 1u) ? eB : -1e9f;
        ebuf[w][lane][jc]      = eA;
        ebuf[w][lane][16 + jc] = eB;
        mA = fmaxf(mA, eA);
        mB = fmaxf(mB, eB);
    }
    #pragma unroll
    for (int off = 32; off > 0; off >>= 1) {
        mA = fmaxf(mA, __shfl_xor(mA, off, 64));
        mB = fmaxf(mB, __shfl_xor(mB, off, 64));
    }

    // pass 2: pe = exp(e - m) (masked -> exact 0), accumulate pe * v for both nodes
    float accA[32], accB[32];
    #pragma unroll
    for (int d = 0; d < 32; d++) { accA[d] = 0.0f; accB[d] = 0.0f; }
    float lsA = 0.0f, lsB = 0.0f;
    #pragma unroll 1
    for (int jc = 0; jc < 16; jc++) {
        float peA = __expf(ebuf[w][lane][jc]      - mA);
        float peB = __expf(ebuf[w][lane][16 + jc] - mB);
        lsA += peA; lsB += peB;
        #pragma unroll
        for (int dq = 0; dq < 8; dq++) {
            float4 v4 = *(const float4*)(wvT + dq * (NN * 4) + jc * 256);
            accA[dq*4+0] = fmaf(peA, v4.x, accA[dq*4+0]);
            accB[dq*4+0] = fmaf(peB, v4.x, accB[dq*4+0]);
            accA[dq*4+1] = fmaf(peA, v4.y, accA[dq*4+1]);
            accB[dq*4+1] = fmaf(peB, v4.y, accB[dq*4+1]);
            accA[dq*4+2] = fmaf(peA, v4.z, accA[dq*4+2]);
            accB[dq*4+2] = fmaf(peB, v4.z, accB[dq*4+2]);
            accA[dq*4+3] = fmaf(peA, v4.w, accA[dq*4+3]);
            accB[dq*4+3] = fmaf(peB, v4.w, accB[dq*4+3]);
        }
    }
    #pragma unroll
    for (int off = 32; off > 0; off >>= 1) {
        lsA += __shfl_xor(lsA, off, 64);
        lsB += __shfl_xor(lsB, off, 64);
    }
    if (lane == 0) {
        invs[2 * p][h]     = 1.0f / lsA;
        invs[2 * p + 1][h] = 1.0f / lsB;
    }
    __syncthreads();   // all e-reads done; ebuf reusable; invs visible

    // acc cross-lane reduce via LDS, 2 rounds (node = 2p + r); region = p*4+h
    float* rbuf = &ebuf[0][0][0];
    {   // round r=0: node iA
        int reg = p * 4 + h;
        #pragma unroll
        for (int d = 0; d < 32; d++) rbuf[(reg * 64 + lane) * 33 + d] = accA[d];
        __syncthreads();
        int g = t >> 6, d = lane & 31, half = lane >> 5;
        float s = 0.0f;
        #pragma unroll
        for (int lq = 0; lq < 32; lq++) s += rbuf[(g * 64 + half * 32 + lq) * 33 + d];
        s += __shfl_xor(s, 32, 64);
        int node = 2 * (g >> 2), hh = g & 3;
        if (half == 0) agg_s[node][hh * 32 + d] = s * invs[node][hh];
        __syncthreads();
    }
    {   // round r=1: node iB
        int reg = p * 4 + h;
        #pragma unroll
        for (int d = 0; d < 32; d++) rbuf[(reg * 64 + lane) * 33 + d] = accB[d];
        __syncthreads();
        int g = t >> 6, d = lane & 31, half = lane >> 5;
        float s = 0.0f;
        #pragma unroll
        for (int lq = 0; lq < 32; lq++) s += rbuf[(g * 64 + half * 32 + lq) * 33 + d];
        s += __shfl_xor(s, 32, 64);
        int node = 2 * (g >> 2) + 1, hh = g & 3;
        if (half == 0) agg_s[node][hh * 32 + d] = s * invs[node][hh];
        __syncthreads();
    }

    // layernorm + residual for the 4 nodes: t -> node n=t>>7, feature f=t&127
    {
        int n = t >> 7, f = t & 127;
        float agg = agg_s[n][f];
        float s = agg, s2 = agg * agg;
        #pragma unroll
        for (int off = 32; off > 0; off >>= 1) {
            s  += __shfl_xor(s,  off, 64);
            s2 += __shfl_xor(s2, off, 64);
        }
        int half = (t >> 6) & 1;
        if (lane == 0) { red2[n][half][0] = s; red2[n][half][1] = s2; }
        __syncthreads();
        float ts  = red2[n][0][0] + red2[n][1][0];
        float ts2 = red2[n][0][1] + red2[n][1][1];
        float mu  = ts  * (1.0f / HID);
        float var = ts2 * (1.0f / HID) - mu * mu;
        float gm = ws[OFF_GAM + l * HID + f];
        float be = ws[OFF_BET + l * HID + f];
        float o = (agg - mu) * rsqrtf(var + 1e-5f) * gm + be;
        ws[OFF_H + (i0 + n) * HID + f] += fmaxf(o, 0.0f);
    }
}

// ---- fused epilogue, 1024 threads/block ----
// blocks 0..63: node_logits + delta_mu heads, 16 nodes/block (wave = node).
// block 64: pooled mean (8 row-groups x 128 rows, unroll-16 ILP) + value head.
// The r4 lesson: the pooled block previously did 512 serial loads/thread with
// unroll-4 -> ~43 us single-block latency tail. Parallelism + ILP fixes it.
__global__ __launch_bounds__(1024) void k_post(float* ws, const unsigned* nf, void* out) {
    bool bf = detect_bf(nf);
    int b = blockIdx.x, t = threadIdx.x;
    if (b < 64) {
        __shared__ float hrow[16][HID];
        int n = t >> 6, tt = t & 63;
        int i = b * 16 + n;
        hrow[n][tt]      = ws[OFF_H + i * HID + tt];
        hrow[n][tt + 64] = ws[OFF_H + i * HID + tt + 64];
        __syncthreads();
        const float* Wn1 = ws + OFF_WN1;
        const float* Wd1 = ws + OFF_WD1;
        float z1 = ws[OFF_BN1 + tt], zd = ws[OFF_BD1 + tt];
        #pragma unroll 4
        for (int k = 0; k < HID; k++) {
            float hk = hrow[n][k];
            z1 += hk * Wn1[k * 64 + tt];
            zd += hk * Wd1[k * 64 + tt];
        }
        z1 = fmaxf(z1, 0.0f); zd = fmaxf(zd, 0.0f);
        float lg = z1 * ws[OFF_WN2 + tt];
        float d0 = zd * ws[OFF_WD2 + tt * 2 + 0];
        float d1 = zd * ws[OFF_WD2 + tt * 2 + 1];
        #pragma unroll
        for (int off = 32; off > 0; off >>= 1) {
            lg += __shfl_xor(lg, off, 64);
            d0 += __shfl_xor(d0, off, 64);
            d1 += __shfl_xor(d1, off, 64);
        }
        if (tt == 0) {
            store_out(out, i,              lg + ws[OFF_BN2],     bf);
            store_out(out, NN + i * 2 + 0, d0 + ws[OFF_BD2 + 0], bf);
            store_out(out, NN + i * 2 + 1, d1 + ws[OFF_BD2 + 1], bf);
        }
    } else {
        __shared__ float part[8][HID];
        __shared__ float pooled[HID];
        int g = t >> 7, c = t & 127;
        float s = 0.0f;
        #pragma unroll 16
        for (int r = 0; r < 128; r++) s += ws[OFF_H + (g * 128 + r) * HID + c];
        part[g][c] = s;
        __syncthreads();
        if (t < HID) {
            float p = 0.0f;
            #pragma unroll
            for (int gg = 0; gg < 8; gg++) p += part[gg][t];
            pooled[t] = p * (1.0f / NN);
        }
        __syncthreads();
        if (t < 64) {
            float z = ws[OFF_BV1 + t];
            float z1 = 0.0f;
            #pragma unroll 8
            for (int k = 0; k < HID; k += 2) {
                z  += pooled[k]     * ws[OFF_WV1 + k * 64 + t];
                z1 += pooled[k + 1] * ws[OFF_WV1 + (k + 1) * 64 + t];
            }
            z = fmaxf(z + z1, 0.0f);
            float pv = z * ws[OFF_WV2 + t];
            #pragma unroll
            for (int off = 32; off > 0; off >>= 1) pv += __shfl_xor(pv, off, 64);
            if (t == 0) store_out(out, 3072, pv + ws[OFF_BV2], bf);
        }
    }
}

extern "C" void kernel_launch(void* const* d_in, const int* in_sizes, int n_in,
                              void* d_out, int out_size, void* d_ws, size_t ws_size,
                              hipStream_t stream) {
    float* ws = (float*)d_ws;
    const unsigned* nf = (const unsigned*)d_in[0];

    P21 ptrs;
    const int map[21] = {0,2,3,4,5,6,7,8,9,10,11,12,13,14,15,16,17,18,19,20,21};
    for (int s = 0; s < 21; s++) ptrs.p[s] = d_in[map[s]];

    // prologue: convert (CB blocks) | mask (NN blocks) | h0 (NN/2 blocks)
    k_pre<<<CB + NN + NN / 2, 256, 0, stream>>>(ptrs, d_in[1], nf, ws);

    for (int l = 0; l < NL; l++) {
        k_mm3<<<dim3(NN / 4, 3), 128, 0, stream>>>(ws, l);
        k_attn<<<NN / 4, 512, 0, stream>>>(ws, l);
    }

    k_post<<<65, 1024, 0, stream>>>(ws, nf, d_out);
}